// Round 3
// baseline (567.198 us; speedup 1.0000x reference)
//
#include <hip/hip_runtime.h>
#include <hip/hip_bf16.h>

// ---- problem constants ----
#define NN   40960
#define EE   327680
#define NN1  20480
#define EE2  163840
#define NN2  10240
#define BB   512
#define NCLS 10

#define ENCNEG 0x007FFFFFu

__device__ __forceinline__ unsigned enc_f(float f) {
    unsigned u = __float_as_uint(f);
    return (u & 0x80000000u) ? ~u : (u | 0x80000000u);
}
__device__ __forceinline__ float dec_f(unsigned u) {
    unsigned v = (u & 0x80000000u) ? (u & 0x7FFFFFFFu) : ~u;
    return __uint_as_float(v);
}
__device__ __forceinline__ float elu_f(float v) { return v > 0.f ? v : (expf(v) - 1.f); }
__device__ __forceinline__ unsigned f2bf_bits(float v) {  // RNE f32->bf16 bits
    unsigned u = __float_as_uint(v);
    return (u + 0x7FFFu + ((u >> 16) & 1u)) >> 16;
}

// ---- init: zero region + enc/batch/mBits (memset folded in) ----
__global__ void init_all(float* zbase, int zcount, unsigned* x1pEnc, unsigned* x2pEnc,
                         int* batch1, int* batch2, unsigned* mBits) {
    int i = blockIdx.x * 256 + threadIdx.x;
    if (i < zcount) zbase[i] = 0.f;
    if (i < NN1 * 32) x1pEnc[i] = ENCNEG;
    if (i < NN2 * 64) x2pEnc[i] = ENCNEG;
    if (i < NN1) batch1[i] = -1073741824;
    if (i < NN2) batch2[i] = -1073741824;
    if (i == 0) *mBits = 0u;
}

// ---- CSR build: degree count for both graphs ----
__global__ void deg_count(const int* __restrict__ ei, const int* __restrict__ ei2,
                          int* deg1, int* deg2) {
    int i = blockIdx.x * 256 + threadIdx.x;
    if (i < EE) atomicAdd(deg1 + ei[EE + i], 1);
    if (i < EE2) atomicAdd(deg2 + ei2[EE2 + i], 1);
}

// ---- two exclusive scans (block 0: graph1, block 1: graph2) ----
__global__ void scan_two(const int* __restrict__ deg1, const int* __restrict__ deg2,
                         int* rowptr1, int* rowptr2, int* cur1, int* cur2) {
    __shared__ int part[1024];
    const int* deg;
    int *rp, *cur, n;
    if (blockIdx.x == 0) { deg = deg1; rp = rowptr1; cur = cur1; n = NN; }
    else                 { deg = deg2; rp = rowptr2; cur = cur2; n = NN1; }
    int t = threadIdx.x;
    int chunk = (n + 1023) / 1024;
    int base = t * chunk;
    int s = 0;
    for (int i = 0; i < chunk; i++) { int idx = base + i; if (idx < n) s += deg[idx]; }
    part[t] = s;
    __syncthreads();
    for (int off = 1; off < 1024; off <<= 1) {
        int u = (t >= off) ? part[t - off] : 0;
        __syncthreads();
        part[t] += u;
        __syncthreads();
    }
    int run = part[t] - s;
    for (int i = 0; i < chunk; i++) {
        int idx = base + i;
        if (idx < n) { rp[idx] = run; cur[idx] = run; run += deg[idx]; }
    }
    if (t == 1023) rp[n] = part[1023];
}

// ---- CSR fill with payloads: graph1 -> {x[src],ax,ay}, graph2 -> src ----
__global__ void fill_csr(const float* __restrict__ x, const float* __restrict__ ea,
                         const int* __restrict__ ei, const int* __restrict__ ei2,
                         int* cur1, int* cur2, float4* eadj1, int* esrc2) {
    int i = blockIdx.x * 256 + threadIdx.x;
    if (i < EE) {
        int s = ei[i], d = ei[EE + i];
        int p = atomicAdd(cur1 + d, 1);
        eadj1[p] = make_float4(x[s], ea[2 * i], ea[2 * i + 1], 0.f);
    }
    if (i < EE2) {
        int s2 = ei2[i], d2 = ei2[EE2 + i];
        int p2 = atomicAdd(cur2 + d2, 1);
        esrc2[p2] = s2;
    }
}

// ---- conv1 gather (fused x1 + pool1 scatter): 32 lanes per node, no LDS ----
__global__ __launch_bounds__(256) void conv1_gather(
    const float* __restrict__ x, const int* __restrict__ rowptr1,
    const float4* __restrict__ eadj1,
    const float* __restrict__ w1, const float* __restrict__ b1,
    const float* __restrict__ w2, const float* __restrict__ b2,
    const float* __restrict__ root1, const float* __restrict__ bias1,
    const float* __restrict__ pos, const int* __restrict__ batch,
    const int* __restrict__ cluster1,
    unsigned* x1pEnc, float* possum, float* ccnt, int* batch1) {
    int t = threadIdx.x;
    int j = t & 31;
    int n = blockIdx.x * 8 + (t >> 5);
    float w2c[25];
#pragma unroll
    for (int k = 0; k < 25; k++) w2c[k] = w2[k * 32 + j];
    float w1x = 0.f, w1y = 0.f, b1j = 0.f;
    if (j < 25) { w1x = w1[j]; w1y = w1[25 + j]; b1j = b1[j]; }
    float b2j = b2[j];
    int r0 = rowptr1[n], r1 = rowptr1[n + 1];
    float acc = 0.f;
    float4 edN = (r0 < r1) ? eadj1[r0] : make_float4(0.f, 0.f, 0.f, 0.f);
    for (int p = r0; p < r1; p++) {
        float4 ed = edN;
        if (p + 1 < r1) edN = eadj1[p + 1];
        float hk = fmaxf(fmaf(ed.y, w1x, fmaf(ed.z, w1y, b1j)), 0.f);
        float m0 = b2j, m1 = 0.f;
#pragma unroll
        for (int k = 0; k < 25; k += 2) {
            m0 = fmaf(__shfl(hk, k, 32), w2c[k], m0);
            if (k + 1 < 25) m1 = fmaf(__shfl(hk, k + 1, 32), w2c[k + 1], m1);
        }
        acc = fmaf(ed.x, m0 + m1, acc);
    }
    float deg = fmaxf((float)(r1 - r0), 1.f);
    float v = fmaf(x[n], root1[j], acc / deg + bias1[j]);
    float x1v = elu_f(v);
    int c = cluster1[n];
    atomicMax(x1pEnc + (size_t)c * 32 + j, enc_f(x1v));
    if (j == 0) {
        atomicAdd(possum + 2 * c, pos[2 * n]);
        atomicAdd(possum + 2 * c + 1, pos[2 * n + 1]);
        atomicAdd(ccnt + c, 1.0f);
        atomicMax(batch1 + c, batch[n]);
    }
}

__global__ void pool1_fin(const unsigned* __restrict__ x1pEnc, const float* __restrict__ possum,
                          const float* __restrict__ ccnt, float* x1p, float* pos1, int* batch1) {
    int idx = blockIdx.x * 256 + threadIdx.x;
    if (idx >= NN1 * 32) return;
    int c = idx >> 5, j = idx & 31;
    unsigned u = x1pEnc[idx];
    x1p[idx] = (u == ENCNEG) ? 0.f : dec_f(u);
    if (j == 0) {
        float cn = fmaxf(ccnt[c], 1.0f);
        pos1[2 * c] = possum[2 * c] / cn;
        pos1[2 * c + 1] = possum[2 * c + 1] / cn;
        int b = batch1[c];
        batch1[c] = b < 0 ? 0 : (b > BB - 1 ? BB - 1 : b);
    }
}

// ---- global max |cart| over pooled edges ----
__global__ void cartmax(const float* __restrict__ pos1, const int* __restrict__ ei2, unsigned* mBits) {
    int e = blockIdx.x * 256 + threadIdx.x;
    float m = 0.f;
    if (e < EE2) {
        int r = ei2[e], c = ei2[EE2 + e];
        m = fmaxf(fabsf(pos1[2 * r] - pos1[2 * c]), fabsf(pos1[2 * r + 1] - pos1[2 * c + 1]));
    }
    for (int off = 32; off; off >>= 1) m = fmaxf(m, __shfl_xor(m, off, 64));
    if ((threadIdx.x & 63) == 0) atomicMax(mBits, __float_as_uint(m));
}

// ---- A2[(n*64+o)*13 + ky] = packed bf16 pair {k=2ky, k=2ky+1} of
//      Σ_i x1p[n,i]·Wext[k, i*64+o]  (k=25 row is b2) ----
__global__ __launch_bounds__(256) void a_gemm(
    const float* __restrict__ x1p, const float* __restrict__ w2,
    const float* __restrict__ b2, unsigned* __restrict__ A2u) {
    __shared__ float Xs[64][36];
    __shared__ float Ws0[32][64];
    __shared__ float Ws1[32][64];
    int t = threadIdx.x;
    int n0 = blockIdx.x * 64;
    int ky = blockIdx.y;  // 0..12
    for (int i = t; i < 64 * 32; i += 256) Xs[i >> 5][i & 31] = x1p[(size_t)n0 * 32 + i];
    const float* wr0 = w2 + (size_t)(2 * ky) * 2048;
    const float* wr1 = (2 * ky + 1 < 25) ? (w2 + (size_t)(2 * ky + 1) * 2048) : b2;
    for (int i = t; i < 2048; i += 256) { Ws0[i >> 6][i & 63] = wr0[i]; Ws1[i >> 6][i & 63] = wr1[i]; }
    __syncthreads();
    int o = t & 63, r0 = t >> 6;
    float a0[16], a1[16];
#pragma unroll
    for (int m = 0; m < 16; m++) { a0[m] = 0.f; a1[m] = 0.f; }
    for (int iq = 0; iq < 8; iq++) {
        float w00 = Ws0[4 * iq][o], w01 = Ws0[4 * iq + 1][o], w02 = Ws0[4 * iq + 2][o], w03 = Ws0[4 * iq + 3][o];
        float w10 = Ws1[4 * iq][o], w11 = Ws1[4 * iq + 1][o], w12 = Ws1[4 * iq + 2][o], w13 = Ws1[4 * iq + 3][o];
#pragma unroll
        for (int m = 0; m < 16; m++) {
            const float4 xv = *(const float4*)&Xs[r0 + 4 * m][4 * iq];
            a0[m] = fmaf(xv.x, w00, fmaf(xv.y, w01, fmaf(xv.z, w02, fmaf(xv.w, w03, a0[m]))));
            a1[m] = fmaf(xv.x, w10, fmaf(xv.y, w11, fmaf(xv.z, w12, fmaf(xv.w, w13, a1[m]))));
        }
    }
#pragma unroll
    for (int m = 0; m < 16; m++) {
        int n = n0 + r0 + 4 * m;
        A2u[((size_t)n * 64 + o) * 13 + ky] = f2bf_bits(a0[m]) | (f2bf_bits(a1[m]) << 16);
    }
}

// ---- conv2 gather (fused x2 + pool2 scatter): 64 lanes per node, no LDS ----
__global__ __launch_bounds__(256) void conv2_gather(
    const unsigned* __restrict__ A2u, const float* __restrict__ pos1,
    const int* __restrict__ rowptr2, const int* __restrict__ esrc2,
    const float* __restrict__ w1, const float* __restrict__ b1,
    const unsigned* __restrict__ mBits,
    const float* __restrict__ x1p, const float* __restrict__ root2,
    const float* __restrict__ bias2,
    const int* __restrict__ cluster2, const int* __restrict__ batch1,
    unsigned* x2pEnc, int* batch2) {
    int t = threadIdx.x;
    int lane = t & 63;
    int n = blockIdx.x * 4 + (t >> 6);
    float Rr[32];
#pragma unroll
    for (int i = 0; i < 32; i++) Rr[i] = root2[i * 64 + lane];
    float w1x = 0.f, w1y = 0.f, b1l = 0.f;
    if (lane < 25) { w1x = w1[lane]; w1y = w1[25 + lane]; b1l = b1[lane]; }
    int r0 = rowptr2[n], r1 = rowptr2[n + 1];
    float inv = 0.5f / __uint_as_float(*mBits);
    float px = pos1[2 * n], py = pos1[2 * n + 1];
    float acc0 = 0.f, acc1 = 0.f;
    int sN = (r0 < r1) ? esrc2[r0] : 0;
    for (int p = r0; p < r1; p++) {
        int s = sN;
        if (p + 1 < r1) sN = esrc2[p + 1];
        const unsigned* Ar = A2u + ((size_t)s * 64 + lane) * 13;
        unsigned uu[13];
#pragma unroll
        for (int c = 0; c < 13; c++) uu[c] = Ar[c];
        float qx = pos1[2 * s], qy = pos1[2 * s + 1];
        float cx = fmaf(qx - px, inv, 0.5f);
        float cy = fmaf(qy - py, inv, 0.5f);
        float ro;
        if (lane < 25) ro = fmaxf(fmaf(cx, w1x, fmaf(cy, w1y, b1l)), 0.f);
        else ro = (lane == 25) ? 1.f : 0.f;
        float m0 = 0.f, m1 = 0.f;
#pragma unroll
        for (int k = 0; k < 26; k += 2) {
            unsigned u = uu[k >> 1];
            float alo = __uint_as_float(u << 16);
            float ahi = __uint_as_float(u & 0xFFFF0000u);
            m0 = fmaf(__shfl(ro, k, 64), alo, m0);
            m1 = fmaf(__shfl(ro, k + 1, 64), ahi, m1);
        }
        acc0 += m0; acc1 += m1;
    }
    float deg = fmaxf((float)(r1 - r0), 1.f);
    float xv = x1p[(size_t)n * 32 + (lane & 31)];
    float ra = bias2[lane];
#pragma unroll
    for (int i = 0; i < 32; i++) ra = fmaf(__shfl(xv, i, 64), Rr[i], ra);
    float x2v = elu_f(ra + (acc0 + acc1) / deg);
    int c = cluster2[n];
    atomicMax(x2pEnc + (size_t)c * 64 + lane, enc_f(x2v));
    if (lane == 0) atomicMax(batch2 + c, batch1[n]);
}

// ---- pool2 finalize + global mean scatter ----
__global__ void pool2_fin(const unsigned* __restrict__ x2pEnc, const int* __restrict__ batch2,
                          float* xgsum, float* gcnt) {
    int idx = blockIdx.x * 256 + threadIdx.x;
    if (idx >= NN2 * 64) return;
    int n2 = idx >> 6, o = idx & 63;
    unsigned u = x2pEnc[idx];
    float v = (u == ENCNEG) ? 0.f : dec_f(u);
    int b = batch2[n2];
    b = b < 0 ? 0 : (b > BB - 1 ? BB - 1 : b);
    atomicAdd(xgsum + (size_t)b * 64 + o, v);
    if (o == 0) atomicAdd(gcnt + b, 1.0f);
}

// ---- head: mean -> fc1+elu -> fc2 -> log_softmax ----
__global__ void head_kernel(const float* __restrict__ xgsum, const float* __restrict__ gcnt,
                            const float* __restrict__ fc1w, const float* __restrict__ fc1b,
                            const float* __restrict__ fc2w, const float* __restrict__ fc2b,
                            float* out) {
    __shared__ float xg[64];
    __shared__ float h[128];
    __shared__ float lg[NCLS];
    __shared__ float red[2];
    int b = blockIdx.x;
    int t = threadIdx.x;
    if (t < 64) xg[t] = xgsum[(size_t)b * 64 + t] / fmaxf(gcnt[b], 1.0f);
    __syncthreads();
    float acc = fc1b[t];
    for (int i = 0; i < 64; i++) acc += xg[i] * fc1w[i * 128 + t];
    h[t] = elu_f(acc);
    __syncthreads();
    if (t < NCLS) {
        float a = fc2b[t];
        for (int j = 0; j < 128; j++) a += h[j] * fc2w[j * NCLS + t];
        lg[t] = a;
    }
    __syncthreads();
    if (t == 0) {
        float mx = lg[0];
        for (int i = 1; i < NCLS; i++) mx = fmaxf(mx, lg[i]);
        float se = 0.f;
        for (int i = 0; i < NCLS; i++) se += expf(lg[i] - mx);
        red[0] = mx;
        red[1] = logf(se);
    }
    __syncthreads();
    if (t < NCLS) out[(size_t)b * NCLS + t] = lg[t] - red[0] - red[1];
}

extern "C" void kernel_launch(void* const* d_in, const int* in_sizes, int n_in,
                              void* d_out, int out_size, void* d_ws, size_t ws_size,
                              hipStream_t stream) {
    const float* x = (const float*)d_in[0];
    const float* pos = (const float*)d_in[1];
    const float* edge_attr = (const float*)d_in[2];
    const int* ei = (const int*)d_in[3];
    const int* batch = (const int*)d_in[4];
    const int* cluster1 = (const int*)d_in[5];
    const int* ei2 = (const int*)d_in[6];
    const int* cluster2 = (const int*)d_in[7];
    const float* nn1_w1 = (const float*)d_in[8];
    const float* nn1_b1 = (const float*)d_in[9];
    const float* nn1_w2 = (const float*)d_in[10];
    const float* nn1_b2 = (const float*)d_in[11];
    const float* root1 = (const float*)d_in[12];
    const float* bias1 = (const float*)d_in[13];
    const float* nn2_w1 = (const float*)d_in[14];
    const float* nn2_b1 = (const float*)d_in[15];
    const float* nn2_w2 = (const float*)d_in[16];
    const float* nn2_b2 = (const float*)d_in[17];
    const float* root2 = (const float*)d_in[18];
    const float* bias2 = (const float*)d_in[19];
    const float* fc1w = (const float*)d_in[20];
    const float* fc1b = (const float*)d_in[21];
    const float* fc2w = (const float*)d_in[22];
    const float* fc2b = (const float*)d_in[23];

    float* ws = (float*)d_ws;
    // ---- workspace layout (float units) ----
    constexpr size_t OFF_POSSUM = 0;                               // NN1*2
    constexpr size_t OFF_CCNT = OFF_POSSUM + (size_t)NN1 * 2;      // NN1
    constexpr size_t OFF_XGSUM = OFF_CCNT + NN1;                   // BB*64
    constexpr size_t OFF_GCNT = OFF_XGSUM + (size_t)BB * 64;       // BB
    constexpr size_t OFF_DEG1 = OFF_GCNT + BB;                     // NN
    constexpr size_t OFF_DEG2 = OFF_DEG1 + NN;                     // NN1
    constexpr size_t ZTOT = OFF_DEG2 + NN1;                        // zero region end
    constexpr size_t OFF_X1PENC = ZTOT;                            // NN1*32 (uint)
    constexpr size_t OFF_X2PENC = OFF_X1PENC + (size_t)NN1 * 32;   // NN2*64 (uint)
    constexpr size_t OFF_BATCH1 = OFF_X2PENC + (size_t)NN2 * 64;   // NN1 (int)
    constexpr size_t OFF_BATCH2 = OFF_BATCH1 + NN1;                // NN2 (int)
    constexpr size_t OFF_MBITS = OFF_BATCH2 + NN2;                 // 4 (uint + pad)
    constexpr size_t OFF_ROWPTR1 = OFF_MBITS + 4;                  // NN+4 (int)
    constexpr size_t OFF_ROWPTR2 = OFF_ROWPTR1 + NN + 4;           // NN1+4 (int)
    constexpr size_t OFF_CUR1 = OFF_ROWPTR2 + NN1 + 4;             // NN (int)
    constexpr size_t OFF_CUR2 = OFF_CUR1 + NN;                     // NN1 (int)
    constexpr size_t OFF_ESRC2 = OFF_CUR2 + NN1;                   // EE2 (int)
    constexpr size_t OFF_X1P = OFF_ESRC2 + EE2;                    // NN1*32
    constexpr size_t OFF_POS1 = OFF_X1P + (size_t)NN1 * 32;        // NN1*2
    constexpr size_t OFF_UNION0 = OFF_POS1 + (size_t)NN1 * 2;
    constexpr size_t OFF_UNION = (OFF_UNION0 + 3) & ~(size_t)3;    // 16B aligned
    // union: eadj1 (EE float4 = EE*4 floats, used until conv1) then A2u (NN1*64*13 uints)

    float* possum = ws + OFF_POSSUM;
    float* ccnt = ws + OFF_CCNT;
    float* xgsum = ws + OFF_XGSUM;
    float* gcnt = ws + OFF_GCNT;
    int* deg1 = (int*)(ws + OFF_DEG1);
    int* deg2 = (int*)(ws + OFF_DEG2);
    unsigned* x1pEnc = (unsigned*)(ws + OFF_X1PENC);
    unsigned* x2pEnc = (unsigned*)(ws + OFF_X2PENC);
    int* batch1 = (int*)(ws + OFF_BATCH1);
    int* batch2 = (int*)(ws + OFF_BATCH2);
    unsigned* mBits = (unsigned*)(ws + OFF_MBITS);
    int* rowptr1 = (int*)(ws + OFF_ROWPTR1);
    int* rowptr2 = (int*)(ws + OFF_ROWPTR2);
    int* cur1 = (int*)(ws + OFF_CUR1);
    int* cur2 = (int*)(ws + OFF_CUR2);
    int* esrc2 = (int*)(ws + OFF_ESRC2);
    float* x1p = ws + OFF_X1P;
    float* pos1 = ws + OFF_POS1;
    float4* eadj1 = (float4*)(ws + OFF_UNION);
    unsigned* A2u = (unsigned*)(ws + OFF_UNION);

    init_all<<<2560, 256, 0, stream>>>(ws, (int)ZTOT, x1pEnc, x2pEnc, batch1, batch2, mBits);
    deg_count<<<EE / 256, 256, 0, stream>>>(ei, ei2, deg1, deg2);
    scan_two<<<2, 1024, 0, stream>>>(deg1, deg2, rowptr1, rowptr2, cur1, cur2);
    fill_csr<<<EE / 256, 256, 0, stream>>>(x, edge_attr, ei, ei2, cur1, cur2, eadj1, esrc2);
    conv1_gather<<<NN / 8, 256, 0, stream>>>(x, rowptr1, eadj1,
                                             nn1_w1, nn1_b1, nn1_w2, nn1_b2, root1, bias1,
                                             pos, batch, cluster1,
                                             x1pEnc, possum, ccnt, batch1);
    pool1_fin<<<NN1 * 32 / 256, 256, 0, stream>>>(x1pEnc, possum, ccnt, x1p, pos1, batch1);
    cartmax<<<EE2 / 256, 256, 0, stream>>>(pos1, ei2, mBits);
    a_gemm<<<dim3(NN1 / 64, 13), 256, 0, stream>>>(x1p, nn2_w2, nn2_b2, A2u);
    conv2_gather<<<NN1 / 4, 256, 0, stream>>>(A2u, pos1, rowptr2, esrc2,
                                              nn2_w1, nn2_b1, mBits, x1p, root2, bias2,
                                              cluster2, batch1, x2pEnc, batch2);
    pool2_fin<<<NN2 * 64 / 256, 256, 0, stream>>>(x2pEnc, batch2, xgsum, gcnt);
    head_kernel<<<BB, 128, 0, stream>>>(xgsum, gcnt, fc1w, fc1b, fc2w, fc2b, (float*)d_out);
}

// Round 4
// 437.058 us; speedup vs baseline: 1.2978x; 1.2978x over previous
//
#include <hip/hip_runtime.h>
#include <hip/hip_bf16.h>

// ---- problem constants ----
#define NN   40960
#define EE   327680
#define NN1  20480
#define EE2  163840
#define NN2  10240
#define BB   512
#define NCLS 10
#define PLANE (NN1 * 64)

#define ENCNEG 0x007FFFFFu

__device__ __forceinline__ unsigned enc_f(float f) {
    unsigned u = __float_as_uint(f);
    return (u & 0x80000000u) ? ~u : (u | 0x80000000u);
}
__device__ __forceinline__ float dec_f(unsigned u) {
    unsigned v = (u & 0x80000000u) ? (u & 0x7FFFFFFFu) : ~u;
    return __uint_as_float(v);
}
__device__ __forceinline__ float elu_f(float v) { return v > 0.f ? v : (expf(v) - 1.f); }
__device__ __forceinline__ unsigned f2bf_bits(float v) {  // RNE f32->bf16 bits
    unsigned u = __float_as_uint(v);
    return (u + 0x7FFFu + ((u >> 16) & 1u)) >> 16;
}

// ---- init: zero region + enc/batch/mBits ----
__global__ void init_all(float* zbase, int zcount, unsigned* x1pEnc, unsigned* x2pEnc,
                         int* batch1, int* batch2, unsigned* mBits) {
    int i = blockIdx.x * 256 + threadIdx.x;
    if (i < zcount) zbase[i] = 0.f;
    if (i < NN1 * 32) x1pEnc[i] = ENCNEG;
    if (i < NN2 * 64) x2pEnc[i] = ENCNEG;
    if (i < NN1) batch1[i] = -1073741824;
    if (i < NN2) batch2[i] = -1073741824;
    if (i == 0) *mBits = 0u;
}

// ---- CSR build: degree count for both graphs ----
__global__ void deg_count(const int* __restrict__ ei, const int* __restrict__ ei2,
                          int* deg1, int* deg2) {
    int i = blockIdx.x * 256 + threadIdx.x;
    if (i < EE) atomicAdd(deg1 + ei[EE + i], 1);
    if (i < EE2) atomicAdd(deg2 + ei2[EE2 + i], 1);
}

// ---- two exclusive scans (block 0: graph1, block 1: graph2) ----
__global__ void scan_two(const int* __restrict__ deg1, const int* __restrict__ deg2,
                         int* rowptr1, int* rowptr2, int* cur1, int* cur2) {
    __shared__ int part[1024];
    const int* deg;
    int *rp, *cur, n;
    if (blockIdx.x == 0) { deg = deg1; rp = rowptr1; cur = cur1; n = NN; }
    else                 { deg = deg2; rp = rowptr2; cur = cur2; n = NN1; }
    int t = threadIdx.x;
    int chunk = (n + 1023) / 1024;
    int base = t * chunk;
    int s = 0;
    for (int i = 0; i < chunk; i++) { int idx = base + i; if (idx < n) s += deg[idx]; }
    part[t] = s;
    __syncthreads();
    for (int off = 1; off < 1024; off <<= 1) {
        int u = (t >= off) ? part[t - off] : 0;
        __syncthreads();
        part[t] += u;
        __syncthreads();
    }
    int run = part[t] - s;
    for (int i = 0; i < chunk; i++) {
        int idx = base + i;
        if (idx < n) { rp[idx] = run; cur[idx] = run; run += deg[idx]; }
    }
    if (t == 1023) rp[n] = part[1023];
}

// ---- CSR fill with payloads: graph1 -> {x[src],ax,ay}, graph2 -> src ----
__global__ void fill_csr(const float* __restrict__ x, const float* __restrict__ ea,
                         const int* __restrict__ ei, const int* __restrict__ ei2,
                         int* cur1, int* cur2, float4* eadj1, int* esrc2) {
    int i = blockIdx.x * 256 + threadIdx.x;
    if (i < EE) {
        int s = ei[i], d = ei[EE + i];
        int p = atomicAdd(cur1 + d, 1);
        eadj1[p] = make_float4(x[s], ea[2 * i], ea[2 * i + 1], 0.f);
    }
    if (i < EE2) {
        int s2 = ei2[i], d2 = ei2[EE2 + i];
        int p2 = atomicAdd(cur2 + d2, 1);
        esrc2[p2] = s2;
    }
}

// ---- conv1 gather: aggregate-then-matvec; 32 lanes per node ----
__global__ __launch_bounds__(256) void conv1_gather(
    const float* __restrict__ x, const int* __restrict__ rowptr1,
    const float4* __restrict__ eadj1,
    const float* __restrict__ w1, const float* __restrict__ b1,
    const float* __restrict__ w2, const float* __restrict__ b2,
    const float* __restrict__ root1, const float* __restrict__ bias1,
    const float* __restrict__ pos, const int* __restrict__ batch,
    const int* __restrict__ cluster1,
    unsigned* x1pEnc, float* possum, float* ccnt, int* batch1) {
    int t = threadIdx.x;
    int j = t & 31;
    int n = blockIdx.x * 8 + (t >> 5);
    float w1x = 0.f, w1y = 0.f, b1j = 0.f;
    if (j < 25) { w1x = w1[j]; w1y = w1[25 + j]; b1j = b1[j]; }
    int r0 = rowptr1[n], r1 = rowptr1[n + 1];
    float agg = 0.f, sumx = 0.f;
    float4 edN = (r0 < r1) ? eadj1[r0] : make_float4(0.f, 0.f, 0.f, 0.f);
    for (int p = r0; p < r1; p++) {
        float4 ed = edN;
        if (p + 1 < r1) edN = eadj1[p + 1];
        float h = fmaxf(fmaf(ed.y, w1x, fmaf(ed.z, w1y, b1j)), 0.f);
        agg = fmaf(ed.x, h, agg);
        sumx += ed.x;
    }
    // per-node 26x32 matvec: lane j computes msg_j
    float w2c[25];
#pragma unroll
    for (int k = 0; k < 25; k++) w2c[k] = w2[k * 32 + j];
    float m = sumx * b2[j];
#pragma unroll
    for (int k = 0; k < 25; k++) m = fmaf(__shfl(agg, k, 32), w2c[k], m);
    float deg = fmaxf((float)(r1 - r0), 1.f);
    float v = fmaf(x[n], root1[j], m / deg + bias1[j]);
    float x1v = elu_f(v);
    int c = cluster1[n];
    atomicMax(x1pEnc + (size_t)c * 32 + j, enc_f(x1v));
    if (j == 0) {
        atomicAdd(possum + 2 * c, pos[2 * n]);
        atomicAdd(possum + 2 * c + 1, pos[2 * n + 1]);
        atomicAdd(ccnt + c, 1.0f);
        atomicMax(batch1 + c, batch[n]);
    }
}

__global__ void pool1_fin(const unsigned* __restrict__ x1pEnc, const float* __restrict__ possum,
                          const float* __restrict__ ccnt, float* x1p, float* pos1, int* batch1) {
    int idx = blockIdx.x * 256 + threadIdx.x;
    if (idx >= NN1 * 32) return;
    int c = idx >> 5, j = idx & 31;
    unsigned u = x1pEnc[idx];
    x1p[idx] = (u == ENCNEG) ? 0.f : dec_f(u);
    if (j == 0) {
        float cn = fmaxf(ccnt[c], 1.0f);
        pos1[2 * c] = possum[2 * c] / cn;
        pos1[2 * c + 1] = possum[2 * c + 1] / cn;
        int b = batch1[c];
        batch1[c] = b < 0 ? 0 : (b > BB - 1 ? BB - 1 : b);
    }
}

// ---- global max |cart| over pooled edges ----
__global__ void cartmax(const float* __restrict__ pos1, const int* __restrict__ ei2, unsigned* mBits) {
    int e = blockIdx.x * 256 + threadIdx.x;
    float m = 0.f;
    if (e < EE2) {
        int r = ei2[e], c = ei2[EE2 + e];
        m = fmaxf(fabsf(pos1[2 * r] - pos1[2 * c]), fabsf(pos1[2 * r + 1] - pos1[2 * c + 1]));
    }
    for (int off = 32; off; off >>= 1) m = fmaxf(m, __shfl_xor(m, off, 64));
    if ((threadIdx.x & 63) == 0) atomicMax(mBits, __float_as_uint(m));
}

// ---- A2 planes: A2u[ky*PLANE + n*64 + o] = packed bf16 {k=2ky, k=2ky+1} of
//      Σ_i x1p[n,i]·Wext[k, i*64+o]  (k=25 row is b2) ----
__global__ __launch_bounds__(256) void a_gemm(
    const float* __restrict__ x1p, const float* __restrict__ w2,
    const float* __restrict__ b2, unsigned* __restrict__ A2u) {
    __shared__ float Xs[64][36];
    __shared__ float Ws0[32][64];
    __shared__ float Ws1[32][64];
    int t = threadIdx.x;
    int n0 = blockIdx.x * 64;
    int ky = blockIdx.y;  // 0..12
    for (int i = t; i < 64 * 32; i += 256) Xs[i >> 5][i & 31] = x1p[(size_t)n0 * 32 + i];
    const float* wr0 = w2 + (size_t)(2 * ky) * 2048;
    const float* wr1 = (2 * ky + 1 < 25) ? (w2 + (size_t)(2 * ky + 1) * 2048) : b2;
    for (int i = t; i < 2048; i += 256) { Ws0[i >> 6][i & 63] = wr0[i]; Ws1[i >> 6][i & 63] = wr1[i]; }
    __syncthreads();
    int o = t & 63, r0 = t >> 6;
    float a0[16], a1[16];
#pragma unroll
    for (int m = 0; m < 16; m++) { a0[m] = 0.f; a1[m] = 0.f; }
    for (int iq = 0; iq < 8; iq++) {
        float w00 = Ws0[4 * iq][o], w01 = Ws0[4 * iq + 1][o], w02 = Ws0[4 * iq + 2][o], w03 = Ws0[4 * iq + 3][o];
        float w10 = Ws1[4 * iq][o], w11 = Ws1[4 * iq + 1][o], w12 = Ws1[4 * iq + 2][o], w13 = Ws1[4 * iq + 3][o];
#pragma unroll
        for (int m = 0; m < 16; m++) {
            const float4 xv = *(const float4*)&Xs[r0 + 4 * m][4 * iq];
            a0[m] = fmaf(xv.x, w00, fmaf(xv.y, w01, fmaf(xv.z, w02, fmaf(xv.w, w03, a0[m]))));
            a1[m] = fmaf(xv.x, w10, fmaf(xv.y, w11, fmaf(xv.z, w12, fmaf(xv.w, w13, a1[m]))));
        }
    }
#pragma unroll
    for (int m = 0; m < 16; m++) {
        int n = n0 + r0 + 4 * m;
        A2u[(size_t)ky * PLANE + (size_t)n * 64 + o] = f2bf_bits(a0[m]) | (f2bf_bits(a1[m]) << 16);
    }
}

// ---- conv2 gather: plane-major A reads with ReLU skip; 64 lanes per node ----
__global__ __launch_bounds__(256) void conv2_gather(
    const unsigned* __restrict__ A2u, const float* __restrict__ pos1,
    const int* __restrict__ rowptr2, const int* __restrict__ esrc2,
    const float* __restrict__ w1, const float* __restrict__ b1,
    const unsigned* __restrict__ mBits,
    const float* __restrict__ x1p, const float* __restrict__ root2,
    const float* __restrict__ bias2,
    const int* __restrict__ cluster2, const int* __restrict__ batch1,
    unsigned* x2pEnc, int* batch2) {
    int t = threadIdx.x;
    int lane = t & 63;
    int n = blockIdx.x * 4 + (t >> 6);
    float Rr[32];
#pragma unroll
    for (int i = 0; i < 32; i++) Rr[i] = root2[i * 64 + lane];
    float w1x = 0.f, w1y = 0.f, b1l = 0.f;
    if (lane < 25) { w1x = w1[lane]; w1y = w1[25 + lane]; b1l = b1[lane]; }
    int r0 = rowptr2[n], r1 = rowptr2[n + 1];
    float inv = 0.5f / __uint_as_float(*mBits);
    float px = pos1[2 * n], py = pos1[2 * n + 1];
    float acc0 = 0.f, acc1 = 0.f;
    int sN = (r0 < r1) ? esrc2[r0] : 0;
    for (int p = r0; p < r1; p++) {
        int s = sN;
        if (p + 1 < r1) sN = esrc2[p + 1];
        float qx = pos1[2 * s], qy = pos1[2 * s + 1];
        float cx = fmaf(qx - px, inv, 0.5f);
        float cy = fmaf(qy - py, inv, 0.5f);
        float ro;
        if (lane < 25) ro = fmaxf(fmaf(cx, w1x, fmaf(cy, w1y, b1l)), 0.f);
        else ro = (lane == 25) ? 1.f : 0.f;
        size_t base = (size_t)s * 64 + lane;
        float ra[13], rb[13];
        unsigned uu[13];
#pragma unroll
        for (int ky = 0; ky < 13; ky++) {
            ra[ky] = __shfl(ro, 2 * ky, 64);
            rb[ky] = __shfl(ro, 2 * ky + 1, 64);
            uu[ky] = (ra[ky] != 0.f || rb[ky] != 0.f) ? A2u[(size_t)ky * PLANE + base] : 0u;
        }
#pragma unroll
        for (int ky = 0; ky < 13; ky++) {
            unsigned u = uu[ky];
            acc0 = fmaf(ra[ky], __uint_as_float(u << 16), acc0);
            acc1 = fmaf(rb[ky], __uint_as_float(u & 0xFFFF0000u), acc1);
        }
    }
    float deg = fmaxf((float)(r1 - r0), 1.f);
    float xv = x1p[(size_t)n * 32 + (lane & 31)];
    float ra2 = bias2[lane];
#pragma unroll
    for (int i = 0; i < 32; i++) ra2 = fmaf(__shfl(xv, i, 64), Rr[i], ra2);
    float x2v = elu_f(ra2 + (acc0 + acc1) / deg);
    int c = cluster2[n];
    atomicMax(x2pEnc + (size_t)c * 64 + lane, enc_f(x2v));
    if (lane == 0) atomicMax(batch2 + c, batch1[n]);
}

// ---- pool2 finalize + global mean scatter ----
__global__ void pool2_fin(const unsigned* __restrict__ x2pEnc, const int* __restrict__ batch2,
                          float* xgsum, float* gcnt) {
    int idx = blockIdx.x * 256 + threadIdx.x;
    if (idx >= NN2 * 64) return;
    int n2 = idx >> 6, o = idx & 63;
    unsigned u = x2pEnc[idx];
    float v = (u == ENCNEG) ? 0.f : dec_f(u);
    int b = batch2[n2];
    b = b < 0 ? 0 : (b > BB - 1 ? BB - 1 : b);
    atomicAdd(xgsum + (size_t)b * 64 + o, v);
    if (o == 0) atomicAdd(gcnt + b, 1.0f);
}

// ---- head: mean -> fc1+elu -> fc2 -> log_softmax ----
__global__ void head_kernel(const float* __restrict__ xgsum, const float* __restrict__ gcnt,
                            const float* __restrict__ fc1w, const float* __restrict__ fc1b,
                            const float* __restrict__ fc2w, const float* __restrict__ fc2b,
                            float* out) {
    __shared__ float xg[64];
    __shared__ float h[128];
    __shared__ float lg[NCLS];
    __shared__ float red[2];
    int b = blockIdx.x;
    int t = threadIdx.x;
    if (t < 64) xg[t] = xgsum[(size_t)b * 64 + t] / fmaxf(gcnt[b], 1.0f);
    __syncthreads();
    float acc = fc1b[t];
    for (int i = 0; i < 64; i++) acc += xg[i] * fc1w[i * 128 + t];
    h[t] = elu_f(acc);
    __syncthreads();
    if (t < NCLS) {
        float a = fc2b[t];
        for (int j = 0; j < 128; j++) a += h[j] * fc2w[j * NCLS + t];
        lg[t] = a;
    }
    __syncthreads();
    if (t == 0) {
        float mx = lg[0];
        for (int i = 1; i < NCLS; i++) mx = fmaxf(mx, lg[i]);
        float se = 0.f;
        for (int i = 0; i < NCLS; i++) se += expf(lg[i] - mx);
        red[0] = mx;
        red[1] = logf(se);
    }
    __syncthreads();
    if (t < NCLS) out[(size_t)b * NCLS + t] = lg[t] - red[0] - red[1];
}

extern "C" void kernel_launch(void* const* d_in, const int* in_sizes, int n_in,
                              void* d_out, int out_size, void* d_ws, size_t ws_size,
                              hipStream_t stream) {
    const float* x = (const float*)d_in[0];
    const float* pos = (const float*)d_in[1];
    const float* edge_attr = (const float*)d_in[2];
    const int* ei = (const int*)d_in[3];
    const int* batch = (const int*)d_in[4];
    const int* cluster1 = (const int*)d_in[5];
    const int* ei2 = (const int*)d_in[6];
    const int* cluster2 = (const int*)d_in[7];
    const float* nn1_w1 = (const float*)d_in[8];
    const float* nn1_b1 = (const float*)d_in[9];
    const float* nn1_w2 = (const float*)d_in[10];
    const float* nn1_b2 = (const float*)d_in[11];
    const float* root1 = (const float*)d_in[12];
    const float* bias1 = (const float*)d_in[13];
    const float* nn2_w1 = (const float*)d_in[14];
    const float* nn2_b1 = (const float*)d_in[15];
    const float* nn2_w2 = (const float*)d_in[16];
    const float* nn2_b2 = (const float*)d_in[17];
    const float* root2 = (const float*)d_in[18];
    const float* bias2 = (const float*)d_in[19];
    const float* fc1w = (const float*)d_in[20];
    const float* fc1b = (const float*)d_in[21];
    const float* fc2w = (const float*)d_in[22];
    const float* fc2b = (const float*)d_in[23];

    float* ws = (float*)d_ws;
    // ---- workspace layout (float units) ----
    constexpr size_t OFF_POSSUM = 0;                               // NN1*2
    constexpr size_t OFF_CCNT = OFF_POSSUM + (size_t)NN1 * 2;      // NN1
    constexpr size_t OFF_XGSUM = OFF_CCNT + NN1;                   // BB*64
    constexpr size_t OFF_GCNT = OFF_XGSUM + (size_t)BB * 64;       // BB
    constexpr size_t OFF_DEG1 = OFF_GCNT + BB;                     // NN
    constexpr size_t OFF_DEG2 = OFF_DEG1 + NN;                     // NN1
    constexpr size_t ZTOT = OFF_DEG2 + NN1;                        // zero region end
    constexpr size_t OFF_X1PENC = ZTOT;                            // NN1*32 (uint)
    constexpr size_t OFF_X2PENC = OFF_X1PENC + (size_t)NN1 * 32;   // NN2*64 (uint)
    constexpr size_t OFF_BATCH1 = OFF_X2PENC + (size_t)NN2 * 64;   // NN1 (int)
    constexpr size_t OFF_BATCH2 = OFF_BATCH1 + NN1;                // NN2 (int)
    constexpr size_t OFF_MBITS = OFF_BATCH2 + NN2;                 // 4 (uint + pad)
    constexpr size_t OFF_ROWPTR1 = OFF_MBITS + 4;                  // NN+4 (int)
    constexpr size_t OFF_ROWPTR2 = OFF_ROWPTR1 + NN + 4;           // NN1+4 (int)
    constexpr size_t OFF_CUR1 = OFF_ROWPTR2 + NN1 + 4;             // NN (int)
    constexpr size_t OFF_CUR2 = OFF_CUR1 + NN;                     // NN1 (int)
    constexpr size_t OFF_ESRC2 = OFF_CUR2 + NN1;                   // EE2 (int)
    constexpr size_t OFF_X1P = OFF_ESRC2 + EE2;                    // NN1*32
    constexpr size_t OFF_POS1 = OFF_X1P + (size_t)NN1 * 32;        // NN1*2
    constexpr size_t OFF_UNION0 = OFF_POS1 + (size_t)NN1 * 2;
    constexpr size_t OFF_UNION = (OFF_UNION0 + 3) & ~(size_t)3;    // 16B aligned
    // union: eadj1 (EE float4, used until conv1) then A2u (13*PLANE uints)

    float* possum = ws + OFF_POSSUM;
    float* ccnt = ws + OFF_CCNT;
    float* xgsum = ws + OFF_XGSUM;
    float* gcnt = ws + OFF_GCNT;
    int* deg1 = (int*)(ws + OFF_DEG1);
    int* deg2 = (int*)(ws + OFF_DEG2);
    unsigned* x1pEnc = (unsigned*)(ws + OFF_X1PENC);
    unsigned* x2pEnc = (unsigned*)(ws + OFF_X2PENC);
    int* batch1 = (int*)(ws + OFF_BATCH1);
    int* batch2 = (int*)(ws + OFF_BATCH2);
    unsigned* mBits = (unsigned*)(ws + OFF_MBITS);
    int* rowptr1 = (int*)(ws + OFF_ROWPTR1);
    int* rowptr2 = (int*)(ws + OFF_ROWPTR2);
    int* cur1 = (int*)(ws + OFF_CUR1);
    int* cur2 = (int*)(ws + OFF_CUR2);
    int* esrc2 = (int*)(ws + OFF_ESRC2);
    float* x1p = ws + OFF_X1P;
    float* pos1 = ws + OFF_POS1;
    float4* eadj1 = (float4*)(ws + OFF_UNION);
    unsigned* A2u = (unsigned*)(ws + OFF_UNION);

    init_all<<<2560, 256, 0, stream>>>(ws, (int)ZTOT, x1pEnc, x2pEnc, batch1, batch2, mBits);
    deg_count<<<EE / 256, 256, 0, stream>>>(ei, ei2, deg1, deg2);
    scan_two<<<2, 1024, 0, stream>>>(deg1, deg2, rowptr1, rowptr2, cur1, cur2);
    fill_csr<<<EE / 256, 256, 0, stream>>>(x, edge_attr, ei, ei2, cur1, cur2, eadj1, esrc2);
    conv1_gather<<<NN / 8, 256, 0, stream>>>(x, rowptr1, eadj1,
                                             nn1_w1, nn1_b1, nn1_w2, nn1_b2, root1, bias1,
                                             pos, batch, cluster1,
                                             x1pEnc, possum, ccnt, batch1);
    pool1_fin<<<NN1 * 32 / 256, 256, 0, stream>>>(x1pEnc, possum, ccnt, x1p, pos1, batch1);
    cartmax<<<EE2 / 256, 256, 0, stream>>>(pos1, ei2, mBits);
    a_gemm<<<dim3(NN1 / 64, 13), 256, 0, stream>>>(x1p, nn2_w2, nn2_b2, A2u);
    conv2_gather<<<NN1 / 4, 256, 0, stream>>>(A2u, pos1, rowptr2, esrc2,
                                              nn2_w1, nn2_b1, mBits, x1p, root2, bias2,
                                              cluster2, batch1, x2pEnc, batch2);
    pool2_fin<<<NN2 * 64 / 256, 256, 0, stream>>>(x2pEnc, batch2, xgsum, gcnt);
    head_kernel<<<BB, 128, 0, stream>>>(xgsum, gcnt, fc1w, fc1b, fc2w, fc2b, (float*)d_out);
}

// Round 5
// 409.438 us; speedup vs baseline: 1.3853x; 1.0675x over previous
//
#include <hip/hip_runtime.h>
#include <hip/hip_bf16.h>

// ---- problem constants ----
#define NN   40960
#define EE   327680
#define NN1  20480
#define EE2  163840
#define NN2  10240
#define BB   512
#define NCLS 10

#define ENCNEG 0x007FFFFFu

__device__ __forceinline__ unsigned enc_f(float f) {
    unsigned u = __float_as_uint(f);
    return (u & 0x80000000u) ? ~u : (u | 0x80000000u);
}
__device__ __forceinline__ float dec_f(unsigned u) {
    unsigned v = (u & 0x80000000u) ? (u & 0x7FFFFFFFu) : ~u;
    return __uint_as_float(v);
}
__device__ __forceinline__ float elu_f(float v) { return v > 0.f ? v : (expf(v) - 1.f); }
__device__ __forceinline__ unsigned f2bf_bits(float v) {  // RNE f32->bf16 bits
    unsigned u = __float_as_uint(v);
    return (u + 0x7FFFu + ((u >> 16) & 1u)) >> 16;
}

// ---- init: zero region + enc/batch/mBits ----
__global__ void init_all(float* zbase, int zcount, unsigned* x1pEnc, unsigned* x2pEnc,
                         int* batch1, int* batch2, unsigned* mBits) {
    int i = blockIdx.x * 256 + threadIdx.x;
    if (i < zcount) zbase[i] = 0.f;
    if (i < NN1 * 32) x1pEnc[i] = ENCNEG;
    if (i < NN2 * 64) x2pEnc[i] = ENCNEG;
    if (i < NN1) batch1[i] = -1073741824;
    if (i < NN2) batch2[i] = -1073741824;
    if (i == 0) *mBits = 0u;
}

// ---- degree count: g1 by dest; g2 by src AND by dest ----
__global__ void deg_count(const int* __restrict__ ei, const int* __restrict__ ei2,
                          int* deg1, int* degS, int* degD) {
    int i = blockIdx.x * 256 + threadIdx.x;
    if (i < EE) atomicAdd(deg1 + ei[EE + i], 1);
    if (i < EE2) {
        atomicAdd(degS + ei2[i], 1);
        atomicAdd(degD + ei2[EE2 + i], 1);
    }
}

// ---- three exclusive scans ----
__global__ void scan_three(const int* __restrict__ deg1, const int* __restrict__ degS,
                           const int* __restrict__ degD,
                           int* rowptr1, int* rowptrS, int* rowptrD,
                           int* cur1, int* curS, int* curD) {
    __shared__ int part[1024];
    const int* deg;
    int *rp, *cur, n;
    if (blockIdx.x == 0)      { deg = deg1; rp = rowptr1; cur = cur1; n = NN; }
    else if (blockIdx.x == 1) { deg = degS; rp = rowptrS; cur = curS; n = NN1; }
    else                      { deg = degD; rp = rowptrD; cur = curD; n = NN1; }
    int t = threadIdx.x;
    int chunk = (n + 1023) / 1024;
    int base = t * chunk;
    int s = 0;
    for (int i = 0; i < chunk; i++) { int idx = base + i; if (idx < n) s += deg[idx]; }
    part[t] = s;
    __syncthreads();
    for (int off = 1; off < 1024; off <<= 1) {
        int u = (t >= off) ? part[t - off] : 0;
        __syncthreads();
        part[t] += u;
        __syncthreads();
    }
    int run = part[t] - s;
    for (int i = 0; i < chunk; i++) {
        int idx = base + i;
        if (idx < n) { rp[idx] = run; cur[idx] = run; run += deg[idx]; }
    }
    if (t == 1023) rp[n] = part[1023];
}

// ---- CSR/CSC fill: g1 dest-CSR payload {x[src],ax,ay}; g2 CSC(dst) + dest-CSR(csc slot) ----
__global__ void fill_csr(const float* __restrict__ x, const float* __restrict__ ea,
                         const int* __restrict__ ei, const int* __restrict__ ei2,
                         int* cur1, int* curS, int* curD,
                         float4* eadj1, int* cscDst, int* dstFrom) {
    int i = blockIdx.x * 256 + threadIdx.x;
    if (i < EE) {
        int s = ei[i], d = ei[EE + i];
        int p = atomicAdd(cur1 + d, 1);
        eadj1[p] = make_float4(x[s], ea[2 * i], ea[2 * i + 1], 0.f);
    }
    if (i < EE2) {
        int s2 = ei2[i], d2 = ei2[EE2 + i];
        int q = atomicAdd(curS + s2, 1);
        cscDst[q] = d2;
        int p2 = atomicAdd(curD + d2, 1);
        dstFrom[p2] = q;
    }
}

// ---- conv1 gather: aggregate-then-matvec; 32 lanes per node ----
__global__ __launch_bounds__(256) void conv1_gather(
    const float* __restrict__ x, const int* __restrict__ rowptr1,
    const float4* __restrict__ eadj1,
    const float* __restrict__ w1, const float* __restrict__ b1,
    const float* __restrict__ w2, const float* __restrict__ b2,
    const float* __restrict__ root1, const float* __restrict__ bias1,
    const float* __restrict__ pos, const int* __restrict__ batch,
    const int* __restrict__ cluster1,
    unsigned* x1pEnc, float* possum, float* ccnt, int* batch1) {
    int t = threadIdx.x;
    int j = t & 31;
    int n = blockIdx.x * 8 + (t >> 5);
    float w1x = 0.f, w1y = 0.f, b1j = 0.f;
    if (j < 25) { w1x = w1[j]; w1y = w1[25 + j]; b1j = b1[j]; }
    int r0 = rowptr1[n], r1 = rowptr1[n + 1];
    float agg = 0.f, sumx = 0.f;
    float4 edN = (r0 < r1) ? eadj1[r0] : make_float4(0.f, 0.f, 0.f, 0.f);
    for (int p = r0; p < r1; p++) {
        float4 ed = edN;
        if (p + 1 < r1) edN = eadj1[p + 1];
        float h = fmaxf(fmaf(ed.y, w1x, fmaf(ed.z, w1y, b1j)), 0.f);
        agg = fmaf(ed.x, h, agg);
        sumx += ed.x;
    }
    float w2c[25];
#pragma unroll
    for (int k = 0; k < 25; k++) w2c[k] = w2[k * 32 + j];
    float m = sumx * b2[j];
#pragma unroll
    for (int k = 0; k < 25; k++) m = fmaf(__shfl(agg, k, 32), w2c[k], m);
    float deg = fmaxf((float)(r1 - r0), 1.f);
    float v = fmaf(x[n], root1[j], m / deg + bias1[j]);
    float x1v = elu_f(v);
    int c = cluster1[n];
    atomicMax(x1pEnc + (size_t)c * 32 + j, enc_f(x1v));
    if (j == 0) {
        atomicAdd(possum + 2 * c, pos[2 * n]);
        atomicAdd(possum + 2 * c + 1, pos[2 * n + 1]);
        atomicAdd(ccnt + c, 1.0f);
        atomicMax(batch1 + c, batch[n]);
    }
}

__global__ void pool1_fin(const unsigned* __restrict__ x1pEnc, const float* __restrict__ possum,
                          const float* __restrict__ ccnt, float* x1p, float* pos1, int* batch1) {
    int idx = blockIdx.x * 256 + threadIdx.x;
    if (idx >= NN1 * 32) return;
    int c = idx >> 5, j = idx & 31;
    unsigned u = x1pEnc[idx];
    x1p[idx] = (u == ENCNEG) ? 0.f : dec_f(u);
    if (j == 0) {
        float cn = fmaxf(ccnt[c], 1.0f);
        pos1[2 * c] = possum[2 * c] / cn;
        pos1[2 * c + 1] = possum[2 * c + 1] / cn;
        int b = batch1[c];
        batch1[c] = b < 0 ? 0 : (b > BB - 1 ? BB - 1 : b);
    }
}

// ---- global max |cart| over pooled edges ----
__global__ void cartmax(const float* __restrict__ pos1, const int* __restrict__ ei2, unsigned* mBits) {
    int e = blockIdx.x * 256 + threadIdx.x;
    float m = 0.f;
    if (e < EE2) {
        int r = ei2[e], c = ei2[EE2 + e];
        m = fmaxf(fabsf(pos1[2 * r] - pos1[2 * c]), fabsf(pos1[2 * r + 1] - pos1[2 * c + 1]));
    }
    for (int off = 32; off; off >>= 1) m = fmaxf(m, __shfl_xor(m, off, 64));
    if ((threadIdx.x & 63) == 0) atomicMax(mBits, __float_as_uint(m));
}

// ---- Au node-major: Au[n*832 + ky*64 + o] = packed bf16 {k=2ky,2ky+1} of
//      Σ_i x1p[n,i]·Wext[k, i*64+o]  (k=25 row is b2) ----
__global__ __launch_bounds__(256) void a_gemm(
    const float* __restrict__ x1p, const float* __restrict__ w2,
    const float* __restrict__ b2, unsigned* __restrict__ Au) {
    __shared__ float Xs[64][36];
    __shared__ float Ws0[32][64];
    __shared__ float Ws1[32][64];
    int t = threadIdx.x;
    int n0 = blockIdx.x * 64;
    int ky = blockIdx.y;  // 0..12
    for (int i = t; i < 64 * 32; i += 256) Xs[i >> 5][i & 31] = x1p[(size_t)n0 * 32 + i];
    const float* wr0 = w2 + (size_t)(2 * ky) * 2048;
    const float* wr1 = (2 * ky + 1 < 25) ? (w2 + (size_t)(2 * ky + 1) * 2048) : b2;
    for (int i = t; i < 2048; i += 256) { Ws0[i >> 6][i & 63] = wr0[i]; Ws1[i >> 6][i & 63] = wr1[i]; }
    __syncthreads();
    int o = t & 63, r0 = t >> 6;
    float a0[16], a1[16];
#pragma unroll
    for (int m = 0; m < 16; m++) { a0[m] = 0.f; a1[m] = 0.f; }
    for (int iq = 0; iq < 8; iq++) {
        float w00 = Ws0[4 * iq][o], w01 = Ws0[4 * iq + 1][o], w02 = Ws0[4 * iq + 2][o], w03 = Ws0[4 * iq + 3][o];
        float w10 = Ws1[4 * iq][o], w11 = Ws1[4 * iq + 1][o], w12 = Ws1[4 * iq + 2][o], w13 = Ws1[4 * iq + 3][o];
#pragma unroll
        for (int m = 0; m < 16; m++) {
            const float4 xv = *(const float4*)&Xs[r0 + 4 * m][4 * iq];
            a0[m] = fmaf(xv.x, w00, fmaf(xv.y, w01, fmaf(xv.z, w02, fmaf(xv.w, w03, a0[m]))));
            a1[m] = fmaf(xv.x, w10, fmaf(xv.y, w11, fmaf(xv.z, w12, fmaf(xv.w, w13, a1[m]))));
        }
    }
#pragma unroll
    for (int m = 0; m < 16; m++) {
        int n = n0 + r0 + 4 * m;
        Au[(size_t)n * 832 + (size_t)ky * 64 + o] = f2bf_bits(a0[m]) | (f2bf_bits(a1[m]) << 16);
    }
}

// ---- conv2 phase 1: per-src streaming; msg -> msgbuf (CSC slot order) ----
__global__ __launch_bounds__(256) void conv2_msg(
    const unsigned* __restrict__ Au, const float* __restrict__ pos1,
    const int* __restrict__ rowptrS, const int* __restrict__ cscDst,
    const float* __restrict__ w1, const float* __restrict__ b1,
    const unsigned* __restrict__ mBits, unsigned short* __restrict__ msgbuf) {
    int t = threadIdx.x;
    int lane = t & 63;
    int s = blockIdx.x * 4 + (t >> 6);
    unsigned au[13];
    const unsigned* Ab = Au + (size_t)s * 832 + lane;
#pragma unroll
    for (int ky = 0; ky < 13; ky++) au[ky] = Ab[ky * 64];
    float w1x = 0.f, w1y = 0.f, b1l = 0.f;
    if (lane < 25) { w1x = w1[lane]; w1y = w1[25 + lane]; b1l = b1[lane]; }
    int r0 = rowptrS[s], r1 = rowptrS[s + 1];
    float inv = 0.5f / __uint_as_float(*mBits);
    float px = pos1[2 * s], py = pos1[2 * s + 1];
    int dN = (r0 < r1) ? cscDst[r0] : 0;
    for (int q = r0; q < r1; q++) {
        int d = dN;
        if (q + 1 < r1) dN = cscDst[q + 1];
        float cx = fmaf(px - pos1[2 * d], inv, 0.5f);
        float cy = fmaf(py - pos1[2 * d + 1], inv, 0.5f);
        float ro;
        if (lane < 25) ro = fmaxf(fmaf(cx, w1x, fmaf(cy, w1y, b1l)), 0.f);
        else ro = (lane == 25) ? 1.f : 0.f;
        float m0 = 0.f, m1 = 0.f;
#pragma unroll
        for (int ky = 0; ky < 13; ky++) {
            float ra = __shfl(ro, 2 * ky, 64);
            float rb = __shfl(ro, 2 * ky + 1, 64);
            unsigned u = au[ky];
            m0 = fmaf(ra, __uint_as_float(u << 16), m0);
            m1 = fmaf(rb, __uint_as_float(u & 0xFFFF0000u), m1);
        }
        msgbuf[(size_t)q * 64 + lane] = (unsigned short)f2bf_bits(m0 + m1);
    }
}

// ---- conv2 phase 2: per-dest sum of msgbuf + fused x2 + pool2 scatter ----
__global__ __launch_bounds__(256) void conv2_fin(
    const unsigned short* __restrict__ msgbuf, const int* __restrict__ rowptrD,
    const int* __restrict__ dstFrom,
    const float* __restrict__ x1p, const float* __restrict__ root2,
    const float* __restrict__ bias2,
    const int* __restrict__ cluster2, const int* __restrict__ batch1,
    unsigned* x2pEnc, int* batch2) {
    int t = threadIdx.x;
    int lane = t & 63;
    int n = blockIdx.x * 4 + (t >> 6);
    float Rr[32];
#pragma unroll
    for (int i = 0; i < 32; i++) Rr[i] = root2[i * 64 + lane];
    int r0 = rowptrD[n], r1 = rowptrD[n + 1];
    float acc = 0.f;
    int qN = (r0 < r1) ? dstFrom[r0] : 0;
    for (int p = r0; p < r1; p++) {
        int q = qN;
        if (p + 1 < r1) qN = dstFrom[p + 1];
        acc += __uint_as_float((unsigned)msgbuf[(size_t)q * 64 + lane] << 16);
    }
    float deg = fmaxf((float)(r1 - r0), 1.f);
    float xv = x1p[(size_t)n * 32 + (lane & 31)];
    float ra2 = bias2[lane];
#pragma unroll
    for (int i = 0; i < 32; i++) ra2 = fmaf(__shfl(xv, i, 64), Rr[i], ra2);
    float x2v = elu_f(ra2 + acc / deg);
    int c = cluster2[n];
    atomicMax(x2pEnc + (size_t)c * 64 + lane, enc_f(x2v));
    if (lane == 0) atomicMax(batch2 + c, batch1[n]);
}

// ---- pool2 finalize + global mean scatter ----
__global__ void pool2_fin(const unsigned* __restrict__ x2pEnc, const int* __restrict__ batch2,
                          float* xgsum, float* gcnt) {
    int idx = blockIdx.x * 256 + threadIdx.x;
    if (idx >= NN2 * 64) return;
    int n2 = idx >> 6, o = idx & 63;
    unsigned u = x2pEnc[idx];
    float v = (u == ENCNEG) ? 0.f : dec_f(u);
    int b = batch2[n2];
    b = b < 0 ? 0 : (b > BB - 1 ? BB - 1 : b);
    atomicAdd(xgsum + (size_t)b * 64 + o, v);
    if (o == 0) atomicAdd(gcnt + b, 1.0f);
}

// ---- head: mean -> fc1+elu -> fc2 -> log_softmax ----
__global__ void head_kernel(const float* __restrict__ xgsum, const float* __restrict__ gcnt,
                            const float* __restrict__ fc1w, const float* __restrict__ fc1b,
                            const float* __restrict__ fc2w, const float* __restrict__ fc2b,
                            float* out) {
    __shared__ float xg[64];
    __shared__ float h[128];
    __shared__ float lg[NCLS];
    __shared__ float red[2];
    int b = blockIdx.x;
    int t = threadIdx.x;
    if (t < 64) xg[t] = xgsum[(size_t)b * 64 + t] / fmaxf(gcnt[b], 1.0f);
    __syncthreads();
    float acc = fc1b[t];
    for (int i = 0; i < 64; i++) acc += xg[i] * fc1w[i * 128 + t];
    h[t] = elu_f(acc);
    __syncthreads();
    if (t < NCLS) {
        float a = fc2b[t];
        for (int j = 0; j < 128; j++) a += h[j] * fc2w[j * NCLS + t];
        lg[t] = a;
    }
    __syncthreads();
    if (t == 0) {
        float mx = lg[0];
        for (int i = 1; i < NCLS; i++) mx = fmaxf(mx, lg[i]);
        float se = 0.f;
        for (int i = 0; i < NCLS; i++) se += expf(lg[i] - mx);
        red[0] = mx;
        red[1] = logf(se);
    }
    __syncthreads();
    if (t < NCLS) out[(size_t)b * NCLS + t] = lg[t] - red[0] - red[1];
}

extern "C" void kernel_launch(void* const* d_in, const int* in_sizes, int n_in,
                              void* d_out, int out_size, void* d_ws, size_t ws_size,
                              hipStream_t stream) {
    const float* x = (const float*)d_in[0];
    const float* pos = (const float*)d_in[1];
    const float* edge_attr = (const float*)d_in[2];
    const int* ei = (const int*)d_in[3];
    const int* batch = (const int*)d_in[4];
    const int* cluster1 = (const int*)d_in[5];
    const int* ei2 = (const int*)d_in[6];
    const int* cluster2 = (const int*)d_in[7];
    const float* nn1_w1 = (const float*)d_in[8];
    const float* nn1_b1 = (const float*)d_in[9];
    const float* nn1_w2 = (const float*)d_in[10];
    const float* nn1_b2 = (const float*)d_in[11];
    const float* root1 = (const float*)d_in[12];
    const float* bias1 = (const float*)d_in[13];
    const float* nn2_w1 = (const float*)d_in[14];
    const float* nn2_b1 = (const float*)d_in[15];
    const float* nn2_w2 = (const float*)d_in[16];
    const float* nn2_b2 = (const float*)d_in[17];
    const float* root2 = (const float*)d_in[18];
    const float* bias2 = (const float*)d_in[19];
    const float* fc1w = (const float*)d_in[20];
    const float* fc1b = (const float*)d_in[21];
    const float* fc2w = (const float*)d_in[22];
    const float* fc2b = (const float*)d_in[23];

    float* ws = (float*)d_ws;
    // ---- workspace layout (float units) ----
    constexpr size_t OFF_POSSUM = 0;                               // NN1*2
    constexpr size_t OFF_CCNT = OFF_POSSUM + (size_t)NN1 * 2;      // NN1
    constexpr size_t OFF_XGSUM = OFF_CCNT + NN1;                   // BB*64
    constexpr size_t OFF_GCNT = OFF_XGSUM + (size_t)BB * 64;       // BB
    constexpr size_t OFF_DEG1 = OFF_GCNT + BB;                     // NN
    constexpr size_t OFF_DEGS = OFF_DEG1 + NN;                     // NN1
    constexpr size_t OFF_DEGD = OFF_DEGS + NN1;                    // NN1
    constexpr size_t ZTOT = OFF_DEGD + NN1;                        // zero region end
    constexpr size_t OFF_X1PENC = ZTOT;                            // NN1*32 (uint)
    constexpr size_t OFF_X2PENC = OFF_X1PENC + (size_t)NN1 * 32;   // NN2*64 (uint)
    constexpr size_t OFF_BATCH1 = OFF_X2PENC + (size_t)NN2 * 64;   // NN1 (int)
    constexpr size_t OFF_BATCH2 = OFF_BATCH1 + NN1;                // NN2 (int)
    constexpr size_t OFF_MBITS = OFF_BATCH2 + NN2;                 // 4 (uint + pad)
    constexpr size_t OFF_ROWPTR1 = OFF_MBITS + 4;                  // NN+4 (int)
    constexpr size_t OFF_ROWPTRS = OFF_ROWPTR1 + NN + 4;           // NN1+4 (int)
    constexpr size_t OFF_ROWPTRD = OFF_ROWPTRS + NN1 + 4;          // NN1+4 (int)
    constexpr size_t OFF_CUR1 = OFF_ROWPTRD + NN1 + 4;             // NN (int)
    constexpr size_t OFF_CURS = OFF_CUR1 + NN;                     // NN1 (int)
    constexpr size_t OFF_CURD = OFF_CURS + NN1;                    // NN1 (int)
    constexpr size_t OFF_CSCDST = OFF_CURD + NN1;                  // EE2 (int)
    constexpr size_t OFF_DSTFROM = OFF_CSCDST + EE2;               // EE2 (int)
    constexpr size_t OFF_X1P = OFF_DSTFROM + EE2;                  // NN1*32
    constexpr size_t OFF_POS1 = OFF_X1P + (size_t)NN1 * 32;        // NN1*2
    constexpr size_t OFF_U0 = OFF_POS1 + (size_t)NN1 * 2;
    constexpr size_t OFF_U = (OFF_U0 + 3) & ~(size_t)3;            // 16B aligned
    // union U: eadj1 (EE float4 = EE*4 floats, dead after conv1)
    //          msgbuf (EE2*64 ushort = EE2*32 floats, used a_gemm-phase onward)
    constexpr size_t USZ = (size_t)EE2 * 32;                       // 5.24M floats (covers both)
    constexpr size_t OFF_AU = OFF_U + USZ;                         // NN1*832 uints (68 MB)

    float* possum = ws + OFF_POSSUM;
    float* ccnt = ws + OFF_CCNT;
    float* xgsum = ws + OFF_XGSUM;
    float* gcnt = ws + OFF_GCNT;
    int* deg1 = (int*)(ws + OFF_DEG1);
    int* degS = (int*)(ws + OFF_DEGS);
    int* degD = (int*)(ws + OFF_DEGD);
    unsigned* x1pEnc = (unsigned*)(ws + OFF_X1PENC);
    unsigned* x2pEnc = (unsigned*)(ws + OFF_X2PENC);
    int* batch1 = (int*)(ws + OFF_BATCH1);
    int* batch2 = (int*)(ws + OFF_BATCH2);
    unsigned* mBits = (unsigned*)(ws + OFF_MBITS);
    int* rowptr1 = (int*)(ws + OFF_ROWPTR1);
    int* rowptrS = (int*)(ws + OFF_ROWPTRS);
    int* rowptrD = (int*)(ws + OFF_ROWPTRD);
    int* cur1 = (int*)(ws + OFF_CUR1);
    int* curS = (int*)(ws + OFF_CURS);
    int* curD = (int*)(ws + OFF_CURD);
    int* cscDst = (int*)(ws + OFF_CSCDST);
    int* dstFrom = (int*)(ws + OFF_DSTFROM);
    float* x1p = ws + OFF_X1P;
    float* pos1 = ws + OFF_POS1;
    float4* eadj1 = (float4*)(ws + OFF_U);
    unsigned short* msgbuf = (unsigned short*)(ws + OFF_U);
    unsigned* Au = (unsigned*)(ws + OFF_AU);

    init_all<<<2560, 256, 0, stream>>>(ws, (int)ZTOT, x1pEnc, x2pEnc, batch1, batch2, mBits);
    deg_count<<<EE / 256, 256, 0, stream>>>(ei, ei2, deg1, degS, degD);
    scan_three<<<3, 1024, 0, stream>>>(deg1, degS, degD, rowptr1, rowptrS, rowptrD,
                                       cur1, curS, curD);
    fill_csr<<<EE / 256, 256, 0, stream>>>(x, edge_attr, ei, ei2, cur1, curS, curD,
                                           eadj1, cscDst, dstFrom);
    conv1_gather<<<NN / 8, 256, 0, stream>>>(x, rowptr1, eadj1,
                                             nn1_w1, nn1_b1, nn1_w2, nn1_b2, root1, bias1,
                                             pos, batch, cluster1,
                                             x1pEnc, possum, ccnt, batch1);
    pool1_fin<<<NN1 * 32 / 256, 256, 0, stream>>>(x1pEnc, possum, ccnt, x1p, pos1, batch1);
    cartmax<<<EE2 / 256, 256, 0, stream>>>(pos1, ei2, mBits);
    a_gemm<<<dim3(NN1 / 64, 13), 256, 0, stream>>>(x1p, nn2_w2, nn2_b2, Au);
    conv2_msg<<<NN1 / 4, 256, 0, stream>>>(Au, pos1, rowptrS, cscDst,
                                           nn2_w1, nn2_b1, mBits, msgbuf);
    conv2_fin<<<NN1 / 4, 256, 0, stream>>>(msgbuf, rowptrD, dstFrom, x1p, root2, bias2,
                                           cluster2, batch1, x2pEnc, batch2);
    pool2_fin<<<NN2 * 64 / 256, 256, 0, stream>>>(x2pEnc, batch2, xgsum, gcnt);
    head_kernel<<<BB, 128, 0, stream>>>(xgsum, gcnt, fc1w, fc1b, fc2w, fc2b, (float*)d_out);
}

// Round 6
// 319.125 us; speedup vs baseline: 1.7774x; 1.2830x over previous
//
#include <hip/hip_runtime.h>
#include <hip/hip_bf16.h>

// ---- problem constants ----
#define NN   40960
#define EE   327680
#define NN1  20480
#define EE2  163840
#define NN2  10240
#define BB   512
#define NCLS 10

// scan geometry: 160 blocks for deg1 (NN), 80 each for degS/degD (NN1)
#define SB1 160
#define SB2 80
#define SBT (SB1 + 2 * SB2)   // 320

#define ENCNEG 0x007FFFFFu

__device__ __forceinline__ unsigned enc_f(float f) {
    unsigned u = __float_as_uint(f);
    return (u & 0x80000000u) ? ~u : (u | 0x80000000u);
}
__device__ __forceinline__ float dec_f(unsigned u) {
    unsigned v = (u & 0x80000000u) ? (u & 0x7FFFFFFFu) : ~u;
    return __uint_as_float(v);
}
__device__ __forceinline__ float elu_f(float v) { return v > 0.f ? v : (expf(v) - 1.f); }
__device__ __forceinline__ unsigned f2bf_bits(float v) {  // RNE f32->bf16 bits
    unsigned u = __float_as_uint(v);
    return (u + 0x7FFFu + ((u >> 16) & 1u)) >> 16;
}

// ---- init: zero region + enc/batch/mBits ----
__global__ void init_all(float* zbase, int zcount, unsigned* x1pEnc, unsigned* x2pEnc,
                         int* batch1, int* batch2, unsigned* mBits) {
    int i = blockIdx.x * 256 + threadIdx.x;
    if (i < zcount) zbase[i] = 0.f;
    if (i < NN1 * 32) x1pEnc[i] = ENCNEG;
    if (i < NN2 * 64) x2pEnc[i] = ENCNEG;
    if (i < NN1) batch1[i] = -1073741824;
    if (i < NN2) batch2[i] = -1073741824;
    if (i == 0) *mBits = 0u;
}

// ---- degree count: g1 by dest; g2 by src AND by dest ----
__global__ void deg_count(const int* __restrict__ ei, const int* __restrict__ ei2,
                          int* deg1, int* degS, int* degD) {
    int i = blockIdx.x * 256 + threadIdx.x;
    if (i < EE) atomicAdd(deg1 + ei[EE + i], 1);
    if (i < EE2) {
        atomicAdd(degS + ei2[i], 1);
        atomicAdd(degD + ei2[EE2 + i], 1);
    }
}

// ---- parallel scan, step 1: per-block partial sums (256 elems/block) ----
__global__ __launch_bounds__(256) void scan_partial(
    const int* __restrict__ deg1, const int* __restrict__ degS,
    const int* __restrict__ degD, int* __restrict__ part) {
    int b = blockIdx.x, t = threadIdx.x;
    const int* src;
    int off;
    if (b < SB1)            { src = deg1; off = b * 256; }
    else if (b < SB1 + SB2) { src = degS; off = (b - SB1) * 256; }
    else                    { src = degD; off = (b - SB1 - SB2) * 256; }
    int v = src[off + t];
#pragma unroll
    for (int o = 32; o; o >>= 1) v += __shfl_down(v, o, 64);
    __shared__ int sred[4];
    if ((t & 63) == 0) sred[t >> 6] = v;
    __syncthreads();
    if (t == 0) part[b] = sred[0] + sred[1] + sred[2] + sred[3];
}

// ---- parallel scan, step 2: segment-exclusive bases of the 320 partials ----
__global__ void scan_base(const int* __restrict__ part, int* __restrict__ partBase,
                          int* rowptr1, int* rowptrS, int* rowptrD) {
    __shared__ int sh[SBT];
    int t = threadIdx.x;
    if (t < SBT) sh[t] = part[t];
    __syncthreads();
    if (t == 0) {
        int run = 0;
        for (int b = 0; b < SB1; b++) { int v = sh[b]; sh[b] = run; run += v; }
        run = 0;
        for (int b = SB1; b < SB1 + SB2; b++) { int v = sh[b]; sh[b] = run; run += v; }
        run = 0;
        for (int b = SB1 + SB2; b < SBT; b++) { int v = sh[b]; sh[b] = run; run += v; }
        rowptr1[NN] = EE;
        rowptrS[NN1] = EE2;
        rowptrD[NN1] = EE2;
    }
    __syncthreads();
    if (t < SBT) partBase[t] = sh[t];
}

// ---- parallel scan, step 3: block exclusive scan + base -> rowptr/cur ----
__global__ __launch_bounds__(256) void scan_apply(
    const int* __restrict__ deg1, const int* __restrict__ degS,
    const int* __restrict__ degD, const int* __restrict__ partBase,
    int* rowptr1, int* rowptrS, int* rowptrD,
    int* cur1, int* curS, int* curD) {
    int b = blockIdx.x, t = threadIdx.x;
    const int* src;
    int *rp, *cur;
    int off;
    if (b < SB1)            { src = deg1; rp = rowptr1; cur = cur1; off = b * 256; }
    else if (b < SB1 + SB2) { src = degS; rp = rowptrS; cur = curS; off = (b - SB1) * 256; }
    else                    { src = degD; rp = rowptrD; cur = curD; off = (b - SB1 - SB2) * 256; }
    __shared__ int sh[256];
    int v = src[off + t];
    sh[t] = v;
    __syncthreads();
#pragma unroll
    for (int o = 1; o < 256; o <<= 1) {
        int u = (t >= o) ? sh[t - o] : 0;
        __syncthreads();
        sh[t] += u;
        __syncthreads();
    }
    int excl = sh[t] - v + partBase[b];
    rp[off + t] = excl;
    cur[off + t] = excl;
}

// ---- CSR/CSC fill: g1 dest-CSR payload {x[src],ax,ay}; g2 CSC(dst) + dest-CSR(csc slot) ----
__global__ void fill_csr(const float* __restrict__ x, const float* __restrict__ ea,
                         const int* __restrict__ ei, const int* __restrict__ ei2,
                         int* cur1, int* curS, int* curD,
                         float4* eadj1, int* cscDst, int* dstFrom) {
    int i = blockIdx.x * 256 + threadIdx.x;
    if (i < EE) {
        int s = ei[i], d = ei[EE + i];
        int p = atomicAdd(cur1 + d, 1);
        eadj1[p] = make_float4(x[s], ea[2 * i], ea[2 * i + 1], 0.f);
    }
    if (i < EE2) {
        int s2 = ei2[i], d2 = ei2[EE2 + i];
        int q = atomicAdd(curS + s2, 1);
        cscDst[q] = d2;
        int p2 = atomicAdd(curD + d2, 1);
        dstFrom[p2] = q;
    }
}

// ---- conv1 gather: aggregate-then-matvec; 32 lanes per node ----
__global__ __launch_bounds__(256) void conv1_gather(
    const float* __restrict__ x, const int* __restrict__ rowptr1,
    const float4* __restrict__ eadj1,
    const float* __restrict__ w1, const float* __restrict__ b1,
    const float* __restrict__ w2, const float* __restrict__ b2,
    const float* __restrict__ root1, const float* __restrict__ bias1,
    const float* __restrict__ pos, const int* __restrict__ batch,
    const int* __restrict__ cluster1,
    unsigned* x1pEnc, float* possum, float* ccnt, int* batch1) {
    int t = threadIdx.x;
    int j = t & 31;
    int n = blockIdx.x * 8 + (t >> 5);
    float w1x = 0.f, w1y = 0.f, b1j = 0.f;
    if (j < 25) { w1x = w1[j]; w1y = w1[25 + j]; b1j = b1[j]; }
    int r0 = rowptr1[n], r1 = rowptr1[n + 1];
    float agg = 0.f, sumx = 0.f;
    float4 edN = (r0 < r1) ? eadj1[r0] : make_float4(0.f, 0.f, 0.f, 0.f);
    for (int p = r0; p < r1; p++) {
        float4 ed = edN;
        if (p + 1 < r1) edN = eadj1[p + 1];
        float h = fmaxf(fmaf(ed.y, w1x, fmaf(ed.z, w1y, b1j)), 0.f);
        agg = fmaf(ed.x, h, agg);
        sumx += ed.x;
    }
    float w2c[25];
#pragma unroll
    for (int k = 0; k < 25; k++) w2c[k] = w2[k * 32 + j];
    float m = sumx * b2[j];
#pragma unroll
    for (int k = 0; k < 25; k++) m = fmaf(__shfl(agg, k, 32), w2c[k], m);
    float deg = fmaxf((float)(r1 - r0), 1.f);
    float v = fmaf(x[n], root1[j], m / deg + bias1[j]);
    float x1v = elu_f(v);
    int c = cluster1[n];
    atomicMax(x1pEnc + (size_t)c * 32 + j, enc_f(x1v));
    if (j == 0) {
        atomicAdd(possum + 2 * c, pos[2 * n]);
        atomicAdd(possum + 2 * c + 1, pos[2 * n + 1]);
        atomicAdd(ccnt + c, 1.0f);
        atomicMax(batch1 + c, batch[n]);
    }
}

__global__ void pool1_fin(const unsigned* __restrict__ x1pEnc, const float* __restrict__ possum,
                          const float* __restrict__ ccnt, float* x1p, float* pos1, int* batch1) {
    int idx = blockIdx.x * 256 + threadIdx.x;
    if (idx >= NN1 * 32) return;
    int c = idx >> 5, j = idx & 31;
    unsigned u = x1pEnc[idx];
    x1p[idx] = (u == ENCNEG) ? 0.f : dec_f(u);
    if (j == 0) {
        float cn = fmaxf(ccnt[c], 1.0f);
        pos1[2 * c] = possum[2 * c] / cn;
        pos1[2 * c + 1] = possum[2 * c + 1] / cn;
        int b = batch1[c];
        batch1[c] = b < 0 ? 0 : (b > BB - 1 ? BB - 1 : b);
    }
}

// ---- global max |cart| over pooled edges ----
__global__ void cartmax(const float* __restrict__ pos1, const int* __restrict__ ei2, unsigned* mBits) {
    int e = blockIdx.x * 256 + threadIdx.x;
    float m = 0.f;
    if (e < EE2) {
        int r = ei2[e], c = ei2[EE2 + e];
        m = fmaxf(fabsf(pos1[2 * r] - pos1[2 * c]), fabsf(pos1[2 * r + 1] - pos1[2 * c + 1]));
    }
    for (int off = 32; off; off >>= 1) m = fmaxf(m, __shfl_xor(m, off, 64));
    if ((threadIdx.x & 63) == 0) atomicMax(mBits, __float_as_uint(m));
}

// ---- Au node-major: Au[n*832 + ky*64 + o] = packed bf16 {k=2ky,2ky+1} of
//      Σ_i x1p[n,i]·Wext[k, i*64+o]  (k=25 row is b2) ----
__global__ __launch_bounds__(256) void a_gemm(
    const float* __restrict__ x1p, const float* __restrict__ w2,
    const float* __restrict__ b2, unsigned* __restrict__ Au) {
    __shared__ float Xs[64][36];
    __shared__ float Ws0[32][64];
    __shared__ float Ws1[32][64];
    int t = threadIdx.x;
    int n0 = blockIdx.x * 64;
    int ky = blockIdx.y;  // 0..12
    for (int i = t; i < 64 * 32; i += 256) Xs[i >> 5][i & 31] = x1p[(size_t)n0 * 32 + i];
    const float* wr0 = w2 + (size_t)(2 * ky) * 2048;
    const float* wr1 = (2 * ky + 1 < 25) ? (w2 + (size_t)(2 * ky + 1) * 2048) : b2;
    for (int i = t; i < 2048; i += 256) { Ws0[i >> 6][i & 63] = wr0[i]; Ws1[i >> 6][i & 63] = wr1[i]; }
    __syncthreads();
    int o = t & 63, r0 = t >> 6;
    float a0[16], a1[16];
#pragma unroll
    for (int m = 0; m < 16; m++) { a0[m] = 0.f; a1[m] = 0.f; }
    for (int iq = 0; iq < 8; iq++) {
        float w00 = Ws0[4 * iq][o], w01 = Ws0[4 * iq + 1][o], w02 = Ws0[4 * iq + 2][o], w03 = Ws0[4 * iq + 3][o];
        float w10 = Ws1[4 * iq][o], w11 = Ws1[4 * iq + 1][o], w12 = Ws1[4 * iq + 2][o], w13 = Ws1[4 * iq + 3][o];
#pragma unroll
        for (int m = 0; m < 16; m++) {
            const float4 xv = *(const float4*)&Xs[r0 + 4 * m][4 * iq];
            a0[m] = fmaf(xv.x, w00, fmaf(xv.y, w01, fmaf(xv.z, w02, fmaf(xv.w, w03, a0[m]))));
            a1[m] = fmaf(xv.x, w10, fmaf(xv.y, w11, fmaf(xv.z, w12, fmaf(xv.w, w13, a1[m]))));
        }
    }
#pragma unroll
    for (int m = 0; m < 16; m++) {
        int n = n0 + r0 + 4 * m;
        Au[(size_t)n * 832 + (size_t)ky * 64 + o] = f2bf_bits(a0[m]) | (f2bf_bits(a1[m]) << 16);
    }
}

// ---- conv2 phase 1: per-src streaming; msg -> msgbuf (CSC slot order) ----
__global__ __launch_bounds__(256) void conv2_msg(
    const unsigned* __restrict__ Au, const float* __restrict__ pos1,
    const int* __restrict__ rowptrS, const int* __restrict__ cscDst,
    const float* __restrict__ w1, const float* __restrict__ b1,
    const unsigned* __restrict__ mBits, unsigned short* __restrict__ msgbuf) {
    int t = threadIdx.x;
    int lane = t & 63;
    int s = blockIdx.x * 4 + (t >> 6);
    unsigned au[13];
    const unsigned* Ab = Au + (size_t)s * 832 + lane;
#pragma unroll
    for (int ky = 0; ky < 13; ky++) au[ky] = Ab[ky * 64];
    float w1x = 0.f, w1y = 0.f, b1l = 0.f;
    if (lane < 25) { w1x = w1[lane]; w1y = w1[25 + lane]; b1l = b1[lane]; }
    int r0 = rowptrS[s], r1 = rowptrS[s + 1];
    float inv = 0.5f / __uint_as_float(*mBits);
    float px = pos1[2 * s], py = pos1[2 * s + 1];
    int dN = (r0 < r1) ? cscDst[r0] : 0;
    for (int q = r0; q < r1; q++) {
        int d = dN;
        if (q + 1 < r1) dN = cscDst[q + 1];
        float cx = fmaf(px - pos1[2 * d], inv, 0.5f);
        float cy = fmaf(py - pos1[2 * d + 1], inv, 0.5f);
        float ro;
        if (lane < 25) ro = fmaxf(fmaf(cx, w1x, fmaf(cy, w1y, b1l)), 0.f);
        else ro = (lane == 25) ? 1.f : 0.f;
        float m0 = 0.f, m1 = 0.f;
#pragma unroll
        for (int ky = 0; ky < 13; ky++) {
            float ra = __shfl(ro, 2 * ky, 64);
            float rb = __shfl(ro, 2 * ky + 1, 64);
            unsigned u = au[ky];
            m0 = fmaf(ra, __uint_as_float(u << 16), m0);
            m1 = fmaf(rb, __uint_as_float(u & 0xFFFF0000u), m1);
        }
        msgbuf[(size_t)q * 64 + lane] = (unsigned short)f2bf_bits(m0 + m1);
    }
}

// ---- conv2 phase 2: per-dest sum of msgbuf + fused x2 + pool2 scatter ----
__global__ __launch_bounds__(256) void conv2_fin(
    const unsigned short* __restrict__ msgbuf, const int* __restrict__ rowptrD,
    const int* __restrict__ dstFrom,
    const float* __restrict__ x1p, const float* __restrict__ root2,
    const float* __restrict__ bias2,
    const int* __restrict__ cluster2, const int* __restrict__ batch1,
    unsigned* x2pEnc, int* batch2) {
    int t = threadIdx.x;
    int lane = t & 63;
    int n = blockIdx.x * 4 + (t >> 6);
    float Rr[32];
#pragma unroll
    for (int i = 0; i < 32; i++) Rr[i] = root2[i * 64 + lane];
    int r0 = rowptrD[n], r1 = rowptrD[n + 1];
    float acc = 0.f;
    int qN = (r0 < r1) ? dstFrom[r0] : 0;
    for (int p = r0; p < r1; p++) {
        int q = qN;
        if (p + 1 < r1) qN = dstFrom[p + 1];
        acc += __uint_as_float((unsigned)msgbuf[(size_t)q * 64 + lane] << 16);
    }
    float deg = fmaxf((float)(r1 - r0), 1.f);
    float xv = x1p[(size_t)n * 32 + (lane & 31)];
    float ra2 = bias2[lane];
#pragma unroll
    for (int i = 0; i < 32; i++) ra2 = fmaf(__shfl(xv, i, 64), Rr[i], ra2);
    float x2v = elu_f(ra2 + acc / deg);
    int c = cluster2[n];
    atomicMax(x2pEnc + (size_t)c * 64 + lane, enc_f(x2v));
    if (lane == 0) atomicMax(batch2 + c, batch1[n]);
}

// ---- pool2 finalize + global mean scatter ----
__global__ void pool2_fin(const unsigned* __restrict__ x2pEnc, const int* __restrict__ batch2,
                          float* xgsum, float* gcnt) {
    int idx = blockIdx.x * 256 + threadIdx.x;
    if (idx >= NN2 * 64) return;
    int n2 = idx >> 6, o = idx & 63;
    unsigned u = x2pEnc[idx];
    float v = (u == ENCNEG) ? 0.f : dec_f(u);
    int b = batch2[n2];
    b = b < 0 ? 0 : (b > BB - 1 ? BB - 1 : b);
    atomicAdd(xgsum + (size_t)b * 64 + o, v);
    if (o == 0) atomicAdd(gcnt + b, 1.0f);
}

// ---- head: mean -> fc1+elu -> fc2 -> log_softmax ----
__global__ void head_kernel(const float* __restrict__ xgsum, const float* __restrict__ gcnt,
                            const float* __restrict__ fc1w, const float* __restrict__ fc1b,
                            const float* __restrict__ fc2w, const float* __restrict__ fc2b,
                            float* out) {
    __shared__ float xg[64];
    __shared__ float h[128];
    __shared__ float lg[NCLS];
    __shared__ float red[2];
    int b = blockIdx.x;
    int t = threadIdx.x;
    if (t < 64) xg[t] = xgsum[(size_t)b * 64 + t] / fmaxf(gcnt[b], 1.0f);
    __syncthreads();
    float acc = fc1b[t];
    for (int i = 0; i < 64; i++) acc += xg[i] * fc1w[i * 128 + t];
    h[t] = elu_f(acc);
    __syncthreads();
    if (t < NCLS) {
        float a = fc2b[t];
        for (int j = 0; j < 128; j++) a += h[j] * fc2w[j * NCLS + t];
        lg[t] = a;
    }
    __syncthreads();
    if (t == 0) {
        float mx = lg[0];
        for (int i = 1; i < NCLS; i++) mx = fmaxf(mx, lg[i]);
        float se = 0.f;
        for (int i = 0; i < NCLS; i++) se += expf(lg[i] - mx);
        red[0] = mx;
        red[1] = logf(se);
    }
    __syncthreads();
    if (t < NCLS) out[(size_t)b * NCLS + t] = lg[t] - red[0] - red[1];
}

extern "C" void kernel_launch(void* const* d_in, const int* in_sizes, int n_in,
                              void* d_out, int out_size, void* d_ws, size_t ws_size,
                              hipStream_t stream) {
    const float* x = (const float*)d_in[0];
    const float* pos = (const float*)d_in[1];
    const float* edge_attr = (const float*)d_in[2];
    const int* ei = (const int*)d_in[3];
    const int* batch = (const int*)d_in[4];
    const int* cluster1 = (const int*)d_in[5];
    const int* ei2 = (const int*)d_in[6];
    const int* cluster2 = (const int*)d_in[7];
    const float* nn1_w1 = (const float*)d_in[8];
    const float* nn1_b1 = (const float*)d_in[9];
    const float* nn1_w2 = (const float*)d_in[10];
    const float* nn1_b2 = (const float*)d_in[11];
    const float* root1 = (const float*)d_in[12];
    const float* bias1 = (const float*)d_in[13];
    const float* nn2_w1 = (const float*)d_in[14];
    const float* nn2_b1 = (const float*)d_in[15];
    const float* nn2_w2 = (const float*)d_in[16];
    const float* nn2_b2 = (const float*)d_in[17];
    const float* root2 = (const float*)d_in[18];
    const float* bias2 = (const float*)d_in[19];
    const float* fc1w = (const float*)d_in[20];
    const float* fc1b = (const float*)d_in[21];
    const float* fc2w = (const float*)d_in[22];
    const float* fc2b = (const float*)d_in[23];

    float* ws = (float*)d_ws;
    // ---- workspace layout (float units) ----
    constexpr size_t OFF_POSSUM = 0;                               // NN1*2
    constexpr size_t OFF_CCNT = OFF_POSSUM + (size_t)NN1 * 2;      // NN1
    constexpr size_t OFF_XGSUM = OFF_CCNT + NN1;                   // BB*64
    constexpr size_t OFF_GCNT = OFF_XGSUM + (size_t)BB * 64;       // BB
    constexpr size_t OFF_DEG1 = OFF_GCNT + BB;                     // NN
    constexpr size_t OFF_DEGS = OFF_DEG1 + NN;                     // NN1
    constexpr size_t OFF_DEGD = OFF_DEGS + NN1;                    // NN1
    constexpr size_t ZTOT = OFF_DEGD + NN1;                        // zero region end
    constexpr size_t OFF_X1PENC = ZTOT;                            // NN1*32 (uint)
    constexpr size_t OFF_X2PENC = OFF_X1PENC + (size_t)NN1 * 32;   // NN2*64 (uint)
    constexpr size_t OFF_BATCH1 = OFF_X2PENC + (size_t)NN2 * 64;   // NN1 (int)
    constexpr size_t OFF_BATCH2 = OFF_BATCH1 + NN1;                // NN2 (int)
    constexpr size_t OFF_MBITS = OFF_BATCH2 + NN2;                 // 4 (uint + pad)
    constexpr size_t OFF_PART = OFF_MBITS + 4;                     // SBT (int)
    constexpr size_t OFF_PBASE = OFF_PART + SBT;                   // SBT (int)
    constexpr size_t OFF_ROWPTR1 = OFF_PBASE + SBT;                // NN+4 (int)
    constexpr size_t OFF_ROWPTRS = OFF_ROWPTR1 + NN + 4;           // NN1+4 (int)
    constexpr size_t OFF_ROWPTRD = OFF_ROWPTRS + NN1 + 4;          // NN1+4 (int)
    constexpr size_t OFF_CUR1 = OFF_ROWPTRD + NN1 + 4;             // NN (int)
    constexpr size_t OFF_CURS = OFF_CUR1 + NN;                     // NN1 (int)
    constexpr size_t OFF_CURD = OFF_CURS + NN1;                    // NN1 (int)
    constexpr size_t OFF_CSCDST = OFF_CURD + NN1;                  // EE2 (int)
    constexpr size_t OFF_DSTFROM = OFF_CSCDST + EE2;               // EE2 (int)
    constexpr size_t OFF_X1P = OFF_DSTFROM + EE2;                  // NN1*32
    constexpr size_t OFF_POS1 = OFF_X1P + (size_t)NN1 * 32;        // NN1*2
    constexpr size_t OFF_U0 = OFF_POS1 + (size_t)NN1 * 2;
    constexpr size_t OFF_U = (OFF_U0 + 3) & ~(size_t)3;            // 16B aligned
    // union U: eadj1 (EE float4 = EE*4 floats, dead after conv1)
    //          msgbuf (EE2*64 ushort = EE2*32 floats, used a_gemm-phase onward)
    constexpr size_t USZ = (size_t)EE2 * 32;                       // covers both
    constexpr size_t OFF_AU = OFF_U + USZ;                         // NN1*832 uints (68 MB)

    float* possum = ws + OFF_POSSUM;
    float* ccnt = ws + OFF_CCNT;
    float* xgsum = ws + OFF_XGSUM;
    float* gcnt = ws + OFF_GCNT;
    int* deg1 = (int*)(ws + OFF_DEG1);
    int* degS = (int*)(ws + OFF_DEGS);
    int* degD = (int*)(ws + OFF_DEGD);
    unsigned* x1pEnc = (unsigned*)(ws + OFF_X1PENC);
    unsigned* x2pEnc = (unsigned*)(ws + OFF_X2PENC);
    int* batch1 = (int*)(ws + OFF_BATCH1);
    int* batch2 = (int*)(ws + OFF_BATCH2);
    unsigned* mBits = (unsigned*)(ws + OFF_MBITS);
    int* part = (int*)(ws + OFF_PART);
    int* partBase = (int*)(ws + OFF_PBASE);
    int* rowptr1 = (int*)(ws + OFF_ROWPTR1);
    int* rowptrS = (int*)(ws + OFF_ROWPTRS);
    int* rowptrD = (int*)(ws + OFF_ROWPTRD);
    int* cur1 = (int*)(ws + OFF_CUR1);
    int* curS = (int*)(ws + OFF_CURS);
    int* curD = (int*)(ws + OFF_CURD);
    int* cscDst = (int*)(ws + OFF_CSCDST);
    int* dstFrom = (int*)(ws + OFF_DSTFROM);
    float* x1p = ws + OFF_X1P;
    float* pos1 = ws + OFF_POS1;
    float4* eadj1 = (float4*)(ws + OFF_U);
    unsigned short* msgbuf = (unsigned short*)(ws + OFF_U);
    unsigned* Au = (unsigned*)(ws + OFF_AU);

    init_all<<<2560, 256, 0, stream>>>(ws, (int)ZTOT, x1pEnc, x2pEnc, batch1, batch2, mBits);
    deg_count<<<EE / 256, 256, 0, stream>>>(ei, ei2, deg1, degS, degD);
    scan_partial<<<SBT, 256, 0, stream>>>(deg1, degS, degD, part);
    scan_base<<<1, 512, 0, stream>>>(part, partBase, rowptr1, rowptrS, rowptrD);
    scan_apply<<<SBT, 256, 0, stream>>>(deg1, degS, degD, partBase,
                                        rowptr1, rowptrS, rowptrD, cur1, curS, curD);
    fill_csr<<<EE / 256, 256, 0, stream>>>(x, edge_attr, ei, ei2, cur1, curS, curD,
                                           eadj1, cscDst, dstFrom);
    conv1_gather<<<NN / 8, 256, 0, stream>>>(x, rowptr1, eadj1,
                                             nn1_w1, nn1_b1, nn1_w2, nn1_b2, root1, bias1,
                                             pos, batch, cluster1,
                                             x1pEnc, possum, ccnt, batch1);
    pool1_fin<<<NN1 * 32 / 256, 256, 0, stream>>>(x1pEnc, possum, ccnt, x1p, pos1, batch1);
    cartmax<<<EE2 / 256, 256, 0, stream>>>(pos1, ei2, mBits);
    a_gemm<<<dim3(NN1 / 64, 13), 256, 0, stream>>>(x1p, nn2_w2, nn2_b2, Au);
    conv2_msg<<<NN1 / 4, 256, 0, stream>>>(Au, pos1, rowptrS, cscDst,
                                           nn2_w1, nn2_b1, mBits, msgbuf);
    conv2_fin<<<NN1 / 4, 256, 0, stream>>>(msgbuf, rowptrD, dstFrom, x1p, root2, bias2,
                                           cluster2, batch1, x2pEnc, batch2);
    pool2_fin<<<NN2 * 64 / 256, 256, 0, stream>>>(x2pEnc, batch2, xgsum, gcnt);
    head_kernel<<<BB, 128, 0, stream>>>(xgsum, gcnt, fc1w, fc1b, fc2w, fc2b, (float*)d_out);
}

// Round 7
// 268.969 us; speedup vs baseline: 2.1088x; 1.1865x over previous
//
#include <hip/hip_runtime.h>
#include <hip/hip_bf16.h>

// ---- problem constants ----
#define NN   40960
#define EE   327680
#define NN1  20480
#define EE2  163840
#define NN2  10240
#define BB   512
#define NCLS 10

// scan geometry: 160 blocks for deg1 (NN), 80 each for degS/degD (NN1)
#define SB1 160
#define SB2 80
#define SBT (SB1 + 2 * SB2)   // 320

#define ENCNEG 0x007FFFFFu

typedef short bf16x8 __attribute__((ext_vector_type(8)));
typedef float f32x4 __attribute__((ext_vector_type(4)));

__device__ __forceinline__ unsigned enc_f(float f) {
    unsigned u = __float_as_uint(f);
    return (u & 0x80000000u) ? ~u : (u | 0x80000000u);
}
__device__ __forceinline__ float dec_f(unsigned u) {
    unsigned v = (u & 0x80000000u) ? (u & 0x7FFFFFFFu) : ~u;
    return __uint_as_float(v);
}
__device__ __forceinline__ float elu_f(float v) { return v > 0.f ? v : (expf(v) - 1.f); }
__device__ __forceinline__ unsigned f2bf_bits(float v) {  // RNE f32->bf16 bits
    unsigned u = __float_as_uint(v);
    return (u + 0x7FFFu + ((u >> 16) & 1u)) >> 16;
}

// ---- init: zero region + enc/batch/mBits ----
__global__ void init_all(float* zbase, int zcount, unsigned* x1pEnc, unsigned* x2pEnc,
                         int* batch1, int* batch2, unsigned* mBits) {
    int i = blockIdx.x * 256 + threadIdx.x;
    if (i < zcount) zbase[i] = 0.f;
    if (i < NN1 * 32) x1pEnc[i] = ENCNEG;
    if (i < NN2 * 64) x2pEnc[i] = ENCNEG;
    if (i < NN1) batch1[i] = -1073741824;
    if (i < NN2) batch2[i] = -1073741824;
    if (i == 0) *mBits = 0u;
}

// ---- degree count: g1 by dest; g2 by src AND by dest ----
__global__ void deg_count(const int* __restrict__ ei, const int* __restrict__ ei2,
                          int* deg1, int* degS, int* degD) {
    int i = blockIdx.x * 256 + threadIdx.x;
    if (i < EE) atomicAdd(deg1 + ei[EE + i], 1);
    if (i < EE2) {
        atomicAdd(degS + ei2[i], 1);
        atomicAdd(degD + ei2[EE2 + i], 1);
    }
}

// ---- parallel scan, step 1: per-block partial sums (256 elems/block) ----
__global__ __launch_bounds__(256) void scan_partial(
    const int* __restrict__ deg1, const int* __restrict__ degS,
    const int* __restrict__ degD, int* __restrict__ part) {
    int b = blockIdx.x, t = threadIdx.x;
    const int* src;
    int off;
    if (b < SB1)            { src = deg1; off = b * 256; }
    else if (b < SB1 + SB2) { src = degS; off = (b - SB1) * 256; }
    else                    { src = degD; off = (b - SB1 - SB2) * 256; }
    int v = src[off + t];
#pragma unroll
    for (int o = 32; o; o >>= 1) v += __shfl_down(v, o, 64);
    __shared__ int sred[4];
    if ((t & 63) == 0) sred[t >> 6] = v;
    __syncthreads();
    if (t == 0) part[b] = sred[0] + sred[1] + sred[2] + sred[3];
}

// ---- parallel scan, step 2: segment-exclusive bases of the 320 partials ----
__global__ void scan_base(const int* __restrict__ part, int* __restrict__ partBase,
                          int* rowptr1, int* rowptrS, int* rowptrD) {
    __shared__ int sh[SBT];
    int t = threadIdx.x;
    if (t < SBT) sh[t] = part[t];
    __syncthreads();
    if (t == 0) {
        int run = 0;
        for (int b = 0; b < SB1; b++) { int v = sh[b]; sh[b] = run; run += v; }
        run = 0;
        for (int b = SB1; b < SB1 + SB2; b++) { int v = sh[b]; sh[b] = run; run += v; }
        run = 0;
        for (int b = SB1 + SB2; b < SBT; b++) { int v = sh[b]; sh[b] = run; run += v; }
        rowptr1[NN] = EE;
        rowptrS[NN1] = EE2;
        rowptrD[NN1] = EE2;
    }
    __syncthreads();
    if (t < SBT) partBase[t] = sh[t];
}

// ---- parallel scan, step 3: block exclusive scan + base -> rowptr/cur ----
__global__ __launch_bounds__(256) void scan_apply(
    const int* __restrict__ deg1, const int* __restrict__ degS,
    const int* __restrict__ degD, const int* __restrict__ partBase,
    int* rowptr1, int* rowptrS, int* rowptrD,
    int* cur1, int* curS, int* curD) {
    int b = blockIdx.x, t = threadIdx.x;
    const int* src;
    int *rp, *cur;
    int off;
    if (b < SB1)            { src = deg1; rp = rowptr1; cur = cur1; off = b * 256; }
    else if (b < SB1 + SB2) { src = degS; rp = rowptrS; cur = curS; off = (b - SB1) * 256; }
    else                    { src = degD; rp = rowptrD; cur = curD; off = (b - SB1 - SB2) * 256; }
    __shared__ int sh[256];
    int v = src[off + t];
    sh[t] = v;
    __syncthreads();
#pragma unroll
    for (int o = 1; o < 256; o <<= 1) {
        int u = (t >= o) ? sh[t - o] : 0;
        __syncthreads();
        sh[t] += u;
        __syncthreads();
    }
    int excl = sh[t] - v + partBase[b];
    rp[off + t] = excl;
    cur[off + t] = excl;
}

// ---- CSR/CSC fill: g1 dest-CSR payload {x[src],ax,ay}; g2 CSC(dst,src) + dest-CSR(csc slot) ----
__global__ void fill_csr(const float* __restrict__ x, const float* __restrict__ ea,
                         const int* __restrict__ ei, const int* __restrict__ ei2,
                         int* cur1, int* curS, int* curD,
                         float4* eadj1, int* cscDst, int* cscSrc, int* dstFrom) {
    int i = blockIdx.x * 256 + threadIdx.x;
    if (i < EE) {
        int s = ei[i], d = ei[EE + i];
        int p = atomicAdd(cur1 + d, 1);
        eadj1[p] = make_float4(x[s], ea[2 * i], ea[2 * i + 1], 0.f);
    }
    if (i < EE2) {
        int s2 = ei2[i], d2 = ei2[EE2 + i];
        int q = atomicAdd(curS + s2, 1);
        cscDst[q] = d2;
        cscSrc[q] = s2;
        int p2 = atomicAdd(curD + d2, 1);
        dstFrom[p2] = q;
    }
}

// ---- conv1 gather: aggregate-then-matvec; 32 lanes per node ----
__global__ __launch_bounds__(256) void conv1_gather(
    const float* __restrict__ x, const int* __restrict__ rowptr1,
    const float4* __restrict__ eadj1,
    const float* __restrict__ w1, const float* __restrict__ b1,
    const float* __restrict__ w2, const float* __restrict__ b2,
    const float* __restrict__ root1, const float* __restrict__ bias1,
    const float* __restrict__ pos, const int* __restrict__ batch,
    const int* __restrict__ cluster1,
    unsigned* x1pEnc, float* possum, float* ccnt, int* batch1) {
    int t = threadIdx.x;
    int j = t & 31;
    int n = blockIdx.x * 8 + (t >> 5);
    float w1x = 0.f, w1y = 0.f, b1j = 0.f;
    if (j < 25) { w1x = w1[j]; w1y = w1[25 + j]; b1j = b1[j]; }
    int r0 = rowptr1[n], r1 = rowptr1[n + 1];
    float agg = 0.f, sumx = 0.f;
    float4 edN = (r0 < r1) ? eadj1[r0] : make_float4(0.f, 0.f, 0.f, 0.f);
    for (int p = r0; p < r1; p++) {
        float4 ed = edN;
        if (p + 1 < r1) edN = eadj1[p + 1];
        float h = fmaxf(fmaf(ed.y, w1x, fmaf(ed.z, w1y, b1j)), 0.f);
        agg = fmaf(ed.x, h, agg);
        sumx += ed.x;
    }
    float w2c[25];
#pragma unroll
    for (int k = 0; k < 25; k++) w2c[k] = w2[k * 32 + j];
    float m = sumx * b2[j];
#pragma unroll
    for (int k = 0; k < 25; k++) m = fmaf(__shfl(agg, k, 32), w2c[k], m);
    float deg = fmaxf((float)(r1 - r0), 1.f);
    float v = fmaf(x[n], root1[j], m / deg + bias1[j]);
    float x1v = elu_f(v);
    int c = cluster1[n];
    atomicMax(x1pEnc + (size_t)c * 32 + j, enc_f(x1v));
    if (j == 0) {
        atomicAdd(possum + 2 * c, pos[2 * n]);
        atomicAdd(possum + 2 * c + 1, pos[2 * n + 1]);
        atomicAdd(ccnt + c, 1.0f);
        atomicMax(batch1 + c, batch[n]);
    }
}

__global__ void pool1_fin(const unsigned* __restrict__ x1pEnc, const float* __restrict__ possum,
                          const float* __restrict__ ccnt, float* x1p, float* pos1, int* batch1) {
    int idx = blockIdx.x * 256 + threadIdx.x;
    if (idx >= NN1 * 32) return;
    int c = idx >> 5, j = idx & 31;
    unsigned u = x1pEnc[idx];
    x1p[idx] = (u == ENCNEG) ? 0.f : dec_f(u);
    if (j == 0) {
        float cn = fmaxf(ccnt[c], 1.0f);
        pos1[2 * c] = possum[2 * c] / cn;
        pos1[2 * c + 1] = possum[2 * c + 1] / cn;
        int b = batch1[c];
        batch1[c] = b < 0 ? 0 : (b > BB - 1 ? BB - 1 : b);
    }
}

// ---- global max |cart| + x1p -> bf16 conversion ----
__global__ void cartmax(const float* __restrict__ pos1, const int* __restrict__ ei2,
                        unsigned* mBits, const float* __restrict__ x1p,
                        unsigned short* __restrict__ x1pb) {
    int e = blockIdx.x * 256 + threadIdx.x;
#pragma unroll
    for (int u = 0; u < 4; u++) {
        int idx = e * 4 + u;  // EE2*4 == NN1*32*... (163840*4 = 655360 = NN1*32)
        x1pb[idx] = (unsigned short)f2bf_bits(x1p[idx]);
    }
    float m = 0.f;
    if (e < EE2) {
        int r = ei2[e], c = ei2[EE2 + e];
        m = fmaxf(fabsf(pos1[2 * r] - pos1[2 * c]), fabsf(pos1[2 * r + 1] - pos1[2 * c + 1]));
    }
    for (int off = 32; off; off >>= 1) m = fmaxf(m, __shfl_xor(m, off, 64));
    if ((threadIdx.x & 63) == 0) atomicMax(mBits, __float_as_uint(m));
}

// ---- build Wext in B-fragment order: WextB[((ky*8+tile)*64+lane)*8+j] ----
// tile = h*4+tt; kmlp = 2ky+h; o = tt*16 + (lane&15); i = (lane>>4)*8 + j
__global__ void prep_wext(const float* __restrict__ w2, const float* __restrict__ b2,
                          unsigned short* __restrict__ WextB) {
    int idx = blockIdx.x * 256 + threadIdx.x;
    if (idx >= 13 * 8 * 64 * 8) return;
    int j = idx & 7;
    int lane = (idx >> 3) & 63;
    int tile = (idx >> 9) & 7;
    int ky = idx >> 12;
    int h = tile >> 2, tt = tile & 3;
    int kmlp = 2 * ky + h;
    int o = tt * 16 + (lane & 15);
    int i = (lane >> 4) * 8 + j;
    float v = (kmlp < 25) ? w2[(size_t)kmlp * 2048 + i * 64 + o] : b2[i * 64 + o];
    WextB[idx] = (unsigned short)f2bf_bits(v);
}

// ---- MFMA A-GEMM: Au[n*832 + ky*64 + o] = pack(bf16 A[n][2ky*64+o], bf16 A[n][(2ky+1)*64+o]) ----
__global__ __launch_bounds__(256) void a_gemm_mfma(
    const unsigned short* __restrict__ x1pb, const unsigned short* __restrict__ WextB,
    unsigned* __restrict__ Au) {
    int t = threadIdx.x;
    int lane = t & 63;
    int w = t >> 6;
    int ky = blockIdx.y;
    int m0 = blockIdx.x * 128 + w * 32;  // 2 M-tiles per wave
    int lo16 = lane & 15, hi4 = lane >> 4;
    bf16x8 bf[8];
    const bf16x8* Bp = (const bf16x8*)(WextB + (size_t)ky * 4096);
#pragma unroll
    for (int i = 0; i < 8; i++) bf[i] = Bp[i * 64 + lane];
    const f32x4 zero = {0.f, 0.f, 0.f, 0.f};
#pragma unroll
    for (int mt = 0; mt < 2; mt++) {
        int mbase = m0 + mt * 16;
        bf16x8 af = *(const bf16x8*)(x1pb + ((size_t)(mbase + lo16) * 32 + hi4 * 8));
        f32x4 acc[8];
#pragma unroll
        for (int i = 0; i < 8; i++)
            acc[i] = __builtin_amdgcn_mfma_f32_16x16x32_bf16(af, bf[i], zero, 0, 0, 0);
#pragma unroll
        for (int tt = 0; tt < 4; tt++) {
#pragma unroll
            for (int j = 0; j < 4; j++) {
                int n = mbase + hi4 * 4 + j;
                unsigned lo = f2bf_bits(acc[tt][j]);
                unsigned hi = f2bf_bits(acc[4 + tt][j]);
                Au[(size_t)n * 832 + ky * 64 + tt * 16 + lo16] = lo | (hi << 16);
            }
        }
    }
}

// ---- per-edge packed bf16 r-vectors (CSC slot order), no cross-lane ops ----
__global__ __launch_bounds__(256) void r2_kernel(
    const int* __restrict__ cscSrc, const int* __restrict__ cscDst,
    const float* __restrict__ pos1, const float* __restrict__ w1,
    const float* __restrict__ b1, const unsigned* __restrict__ mBits,
    unsigned* __restrict__ r2) {
    int q = blockIdx.x * 256 + threadIdx.x;
    if (q >= EE2) return;
    int s = cscSrc[q], d = cscDst[q];
    float inv = 0.5f / __uint_as_float(*mBits);
    float2 ps = ((const float2*)pos1)[s];
    float2 pd = ((const float2*)pos1)[d];
    float cx = fmaf(ps.x - pd.x, inv, 0.5f);
    float cy = fmaf(ps.y - pd.y, inv, 0.5f);
    unsigned out[13];
#pragma unroll
    for (int ky = 0; ky < 13; ky++) {
        int k0 = 2 * ky, k1 = 2 * ky + 1;
        float rlo = fmaxf(fmaf(cx, w1[k0], fmaf(cy, w1[25 + k0], b1[k0])), 0.f);
        float rhi = 1.f;
        if (k1 < 25) rhi = fmaxf(fmaf(cx, w1[k1], fmaf(cy, w1[25 + k1], b1[k1])), 0.f);
        out[ky] = f2bf_bits(rlo) | (f2bf_bits(rhi) << 16);
    }
#pragma unroll
    for (int ky = 0; ky < 13; ky++) r2[(size_t)q * 13 + ky] = out[ky];
}

// ---- conv2 phase 1: per-src streaming; msg = r2[q] . Au[s]; no shuffles ----
__global__ __launch_bounds__(256) void conv2_msg(
    const unsigned* __restrict__ Au, const unsigned* __restrict__ r2,
    const int* __restrict__ rowptrS, unsigned short* __restrict__ msgbuf) {
    int t = threadIdx.x;
    int lane = t & 63;
    int s = __builtin_amdgcn_readfirstlane(blockIdx.x * 4 + (t >> 6));
    unsigned au[13];
    const unsigned* Ab = Au + (size_t)s * 832 + lane;
#pragma unroll
    for (int ky = 0; ky < 13; ky++) au[ky] = Ab[ky * 64];
    int r0 = rowptrS[s], r1 = rowptrS[s + 1];
    for (int q = r0; q < r1; q++) {
        const unsigned* rr = r2 + (size_t)q * 13;  // wave-uniform -> scalar loads
        float m0 = 0.f, m1 = 0.f;
#pragma unroll
        for (int ky = 0; ky < 13; ky++) {
            unsigned rp = rr[ky];
            unsigned ua = au[ky];
            m0 = fmaf(__uint_as_float(rp << 16), __uint_as_float(ua << 16), m0);
            m1 = fmaf(__uint_as_float(rp & 0xFFFF0000u), __uint_as_float(ua & 0xFFFF0000u), m1);
        }
        msgbuf[(size_t)q * 64 + lane] = (unsigned short)f2bf_bits(m0 + m1);
    }
}

// ---- conv2 phase 2: per-dest sum of msgbuf + fused x2 + pool2 scatter ----
__global__ __launch_bounds__(256) void conv2_fin(
    const unsigned short* __restrict__ msgbuf, const int* __restrict__ rowptrD,
    const int* __restrict__ dstFrom,
    const float* __restrict__ x1p, const float* __restrict__ root2,
    const float* __restrict__ bias2,
    const int* __restrict__ cluster2, const int* __restrict__ batch1,
    unsigned* x2pEnc, int* batch2) {
    int t = threadIdx.x;
    int lane = t & 63;
    int n = blockIdx.x * 4 + (t >> 6);
    float Rr[32];
#pragma unroll
    for (int i = 0; i < 32; i++) Rr[i] = root2[i * 64 + lane];
    int r0 = rowptrD[n], r1 = rowptrD[n + 1];
    float acc = 0.f;
    int qN = (r0 < r1) ? dstFrom[r0] : 0;
    for (int p = r0; p < r1; p++) {
        int q = qN;
        if (p + 1 < r1) qN = dstFrom[p + 1];
        acc += __uint_as_float((unsigned)msgbuf[(size_t)q * 64 + lane] << 16);
    }
    float deg = fmaxf((float)(r1 - r0), 1.f);
    float xv = x1p[(size_t)n * 32 + (lane & 31)];
    float ra2 = bias2[lane];
#pragma unroll
    for (int i = 0; i < 32; i++) ra2 = fmaf(__shfl(xv, i, 64), Rr[i], ra2);
    float x2v = elu_f(ra2 + acc / deg);
    int c = cluster2[n];
    atomicMax(x2pEnc + (size_t)c * 64 + lane, enc_f(x2v));
    if (lane == 0) atomicMax(batch2 + c, batch1[n]);
}

// ---- pool2 finalize + global mean scatter ----
__global__ void pool2_fin(const unsigned* __restrict__ x2pEnc, const int* __restrict__ batch2,
                          float* xgsum, float* gcnt) {
    int idx = blockIdx.x * 256 + threadIdx.x;
    if (idx >= NN2 * 64) return;
    int n2 = idx >> 6, o = idx & 63;
    unsigned u = x2pEnc[idx];
    float v = (u == ENCNEG) ? 0.f : dec_f(u);
    int b = batch2[n2];
    b = b < 0 ? 0 : (b > BB - 1 ? BB - 1 : b);
    atomicAdd(xgsum + (size_t)b * 64 + o, v);
    if (o == 0) atomicAdd(gcnt + b, 1.0f);
}

// ---- head: mean -> fc1+elu -> fc2 -> log_softmax ----
__global__ void head_kernel(const float* __restrict__ xgsum, const float* __restrict__ gcnt,
                            const float* __restrict__ fc1w, const float* __restrict__ fc1b,
                            const float* __restrict__ fc2w, const float* __restrict__ fc2b,
                            float* out) {
    __shared__ float xg[64];
    __shared__ float h[128];
    __shared__ float lg[NCLS];
    __shared__ float red[2];
    int b = blockIdx.x;
    int t = threadIdx.x;
    if (t < 64) xg[t] = xgsum[(size_t)b * 64 + t] / fmaxf(gcnt[b], 1.0f);
    __syncthreads();
    float acc = fc1b[t];
    for (int i = 0; i < 64; i++) acc += xg[i] * fc1w[i * 128 + t];
    h[t] = elu_f(acc);
    __syncthreads();
    if (t < NCLS) {
        float a = fc2b[t];
        for (int j = 0; j < 128; j++) a += h[j] * fc2w[j * NCLS + t];
        lg[t] = a;
    }
    __syncthreads();
    if (t == 0) {
        float mx = lg[0];
        for (int i = 1; i < NCLS; i++) mx = fmaxf(mx, lg[i]);
        float se = 0.f;
        for (int i = 0; i < NCLS; i++) se += expf(lg[i] - mx);
        red[0] = mx;
        red[1] = logf(se);
    }
    __syncthreads();
    if (t < NCLS) out[(size_t)b * NCLS + t] = lg[t] - red[0] - red[1];
}

extern "C" void kernel_launch(void* const* d_in, const int* in_sizes, int n_in,
                              void* d_out, int out_size, void* d_ws, size_t ws_size,
                              hipStream_t stream) {
    const float* x = (const float*)d_in[0];
    const float* pos = (const float*)d_in[1];
    const float* edge_attr = (const float*)d_in[2];
    const int* ei = (const int*)d_in[3];
    const int* batch = (const int*)d_in[4];
    const int* cluster1 = (const int*)d_in[5];
    const int* ei2 = (const int*)d_in[6];
    const int* cluster2 = (const int*)d_in[7];
    const float* nn1_w1 = (const float*)d_in[8];
    const float* nn1_b1 = (const float*)d_in[9];
    const float* nn1_w2 = (const float*)d_in[10];
    const float* nn1_b2 = (const float*)d_in[11];
    const float* root1 = (const float*)d_in[12];
    const float* bias1 = (const float*)d_in[13];
    const float* nn2_w1 = (const float*)d_in[14];
    const float* nn2_b1 = (const float*)d_in[15];
    const float* nn2_w2 = (const float*)d_in[16];
    const float* nn2_b2 = (const float*)d_in[17];
    const float* root2 = (const float*)d_in[18];
    const float* bias2 = (const float*)d_in[19];
    const float* fc1w = (const float*)d_in[20];
    const float* fc1b = (const float*)d_in[21];
    const float* fc2w = (const float*)d_in[22];
    const float* fc2b = (const float*)d_in[23];

    float* ws = (float*)d_ws;
    // ---- workspace layout (float units) ----
    constexpr size_t OFF_POSSUM = 0;                               // NN1*2
    constexpr size_t OFF_CCNT = OFF_POSSUM + (size_t)NN1 * 2;      // NN1
    constexpr size_t OFF_XGSUM = OFF_CCNT + NN1;                   // BB*64
    constexpr size_t OFF_GCNT = OFF_XGSUM + (size_t)BB * 64;       // BB
    constexpr size_t OFF_DEG1 = OFF_GCNT + BB;                     // NN
    constexpr size_t OFF_DEGS = OFF_DEG1 + NN;                     // NN1
    constexpr size_t OFF_DEGD = OFF_DEGS + NN1;                    // NN1
    constexpr size_t ZTOT = OFF_DEGD + NN1;                        // zero region end
    constexpr size_t OFF_X1PENC = ZTOT;                            // NN1*32 (uint); x1pb overlays (ushort NN1*32)
    constexpr size_t OFF_X2PENC = OFF_X1PENC + (size_t)NN1 * 32;   // NN2*64 (uint)
    constexpr size_t OFF_BATCH1 = OFF_X2PENC + (size_t)NN2 * 64;   // NN1 (int)
    constexpr size_t OFF_BATCH2 = OFF_BATCH1 + NN1;                // NN2 (int)
    constexpr size_t OFF_MBITS = OFF_BATCH2 + NN2;                 // 4 (uint + pad)
    constexpr size_t OFF_PART = OFF_MBITS + 4;                     // SBT (int)
    constexpr size_t OFF_PBASE = OFF_PART + SBT;                   // SBT (int)
    constexpr size_t OFF_ROWPTR1 = OFF_PBASE + SBT;                // NN+4 (int)
    constexpr size_t OFF_ROWPTRS = OFF_ROWPTR1 + NN + 4;           // NN1+4 (int)
    constexpr size_t OFF_ROWPTRD = OFF_ROWPTRS + NN1 + 4;          // NN1+4 (int)
    constexpr size_t OFF_CUR1 = OFF_ROWPTRD + NN1 + 4;             // NN (int)
    constexpr size_t OFF_CURS = OFF_CUR1 + NN;                     // NN1 (int)
    constexpr size_t OFF_CURD = OFF_CURS + NN1;                    // NN1 (int)
    constexpr size_t OFF_CSCDST = OFF_CURD + NN1;                  // EE2 (int)
    constexpr size_t OFF_CSCSRC = OFF_CSCDST + EE2;                // EE2 (int)
    constexpr size_t OFF_DSTFROM = OFF_CSCSRC + EE2;               // EE2 (int)
    constexpr size_t OFF_X1P = OFF_DSTFROM + EE2;                  // NN1*32
    constexpr size_t OFF_POS1 = OFF_X1P + (size_t)NN1 * 32;        // NN1*2
    constexpr size_t OFF_WEXTB0 = OFF_POS1 + (size_t)NN1 * 2;
    constexpr size_t OFF_WEXTB = (OFF_WEXTB0 + 3) & ~(size_t)3;    // 13*8*64*8 ushort = 26624 floats
    constexpr size_t OFF_UA0 = OFF_WEXTB + 26624;
    constexpr size_t OFF_UA = (OFF_UA0 + 3) & ~(size_t)3;          // union: eadj1 (EE*4) / r2 (EE2*13)
    constexpr size_t UASZ = (size_t)EE2 * 13;                      // 2.13M >= EE*4 (1.31M)
    constexpr size_t OFF_MSG0 = OFF_UA + UASZ;
    constexpr size_t OFF_MSG = (OFF_MSG0 + 3) & ~(size_t)3;        // msgbuf EE2*64 ushort = EE2*32 floats
    constexpr size_t OFF_AU = OFF_MSG + (size_t)EE2 * 32;          // NN1*832 (uint)

    float* possum = ws + OFF_POSSUM;
    float* ccnt = ws + OFF_CCNT;
    float* xgsum = ws + OFF_XGSUM;
    float* gcnt = ws + OFF_GCNT;
    int* deg1 = (int*)(ws + OFF_DEG1);
    int* degS = (int*)(ws + OFF_DEGS);
    int* degD = (int*)(ws + OFF_DEGD);
    unsigned* x1pEnc = (unsigned*)(ws + OFF_X1PENC);
    unsigned short* x1pb = (unsigned short*)(ws + OFF_X1PENC);     // overlay (after pool1_fin)
    unsigned* x2pEnc = (unsigned*)(ws + OFF_X2PENC);
    int* batch1 = (int*)(ws + OFF_BATCH1);
    int* batch2 = (int*)(ws + OFF_BATCH2);
    unsigned* mBits = (unsigned*)(ws + OFF_MBITS);
    int* part = (int*)(ws + OFF_PART);
    int* partBase = (int*)(ws + OFF_PBASE);
    int* rowptr1 = (int*)(ws + OFF_ROWPTR1);
    int* rowptrS = (int*)(ws + OFF_ROWPTRS);
    int* rowptrD = (int*)(ws + OFF_ROWPTRD);
    int* cur1 = (int*)(ws + OFF_CUR1);
    int* curS = (int*)(ws + OFF_CURS);
    int* curD = (int*)(ws + OFF_CURD);
    int* cscDst = (int*)(ws + OFF_CSCDST);
    int* cscSrc = (int*)(ws + OFF_CSCSRC);
    int* dstFrom = (int*)(ws + OFF_DSTFROM);
    float* x1p = ws + OFF_X1P;
    float* pos1 = ws + OFF_POS1;
    unsigned short* WextB = (unsigned short*)(ws + OFF_WEXTB);
    float4* eadj1 = (float4*)(ws + OFF_UA);
    unsigned* r2 = (unsigned*)(ws + OFF_UA);
    unsigned short* msgbuf = (unsigned short*)(ws + OFF_MSG);
    unsigned* Au = (unsigned*)(ws + OFF_AU);

    init_all<<<2560, 256, 0, stream>>>(ws, (int)ZTOT, x1pEnc, x2pEnc, batch1, batch2, mBits);
    deg_count<<<EE / 256, 256, 0, stream>>>(ei, ei2, deg1, degS, degD);
    scan_partial<<<SBT, 256, 0, stream>>>(deg1, degS, degD, part);
    scan_base<<<1, 512, 0, stream>>>(part, partBase, rowptr1, rowptrS, rowptrD);
    scan_apply<<<SBT, 256, 0, stream>>>(deg1, degS, degD, partBase,
                                        rowptr1, rowptrS, rowptrD, cur1, curS, curD);
    fill_csr<<<EE / 256, 256, 0, stream>>>(x, edge_attr, ei, ei2, cur1, curS, curD,
                                           eadj1, cscDst, cscSrc, dstFrom);
    prep_wext<<<208, 256, 0, stream>>>(nn2_w2, nn2_b2, WextB);
    conv1_gather<<<NN / 8, 256, 0, stream>>>(x, rowptr1, eadj1,
                                             nn1_w1, nn1_b1, nn1_w2, nn1_b2, root1, bias1,
                                             pos, batch, cluster1,
                                             x1pEnc, possum, ccnt, batch1);
    pool1_fin<<<NN1 * 32 / 256, 256, 0, stream>>>(x1pEnc, possum, ccnt, x1p, pos1, batch1);
    cartmax<<<EE2 / 256, 256, 0, stream>>>(pos1, ei2, mBits, x1p, x1pb);
    a_gemm_mfma<<<dim3(NN1 / 128, 13), 256, 0, stream>>>(x1pb, WextB, Au);
    r2_kernel<<<EE2 / 256, 256, 0, stream>>>(cscSrc, cscDst, pos1, nn2_w1, nn2_b1, mBits, r2);
    conv2_msg<<<NN1 / 4, 256, 0, stream>>>(Au, r2, rowptrS, msgbuf);
    conv2_fin<<<NN1 / 4, 256, 0, stream>>>(msgbuf, rowptrD, dstFrom, x1p, root2, bias2,
                                           cluster2, batch1, x2pEnc, batch2);
    pool2_fin<<<NN2 * 64 / 256, 256, 0, stream>>>(x2pEnc, batch2, xgsum, gcnt);
    head_kernel<<<BB, 128, 0, stream>>>(xgsum, gcnt, fc1w, fc1b, fc2w, fc2b, (float*)d_out);
}